// Round 2
// baseline (5474.767 us; speedup 1.0000x reference)
//
#include <hip/hip_runtime.h>
#include <hip/hip_bf16.h>

namespace {

constexpr int Bc = 64, Tc = 96, Fc = 48, Hc = 128, Ac = 8;
constexpr int DFFc = 512, DEMOc = 12, NHc = 4, Nc = 49, H3c = 384, DKc = 32;
constexpr int BCH = 4;  // batches per GRU block

__device__ __forceinline__ float sigf(float x) { return 1.f / (1.f + expf(-x)); }

template <typename ST> __device__ __forceinline__ void stv(ST* p, float v);
template <> __device__ __forceinline__ void stv<float>(float* p, float v) { *p = v; }
template <> __device__ __forceinline__ void stv<__hip_bfloat16>(__hip_bfloat16* p, float v) {
  *p = __float2bfloat16(v);
}

template <typename ST> __device__ __forceinline__ void ld4(const ST* p, float* o);
template <> __device__ __forceinline__ void ld4<float>(const float* p, float* o) {
  float4 v = *reinterpret_cast<const float4*>(p);
  o[0] = v.x; o[1] = v.y; o[2] = v.z; o[3] = v.w;
}
template <> __device__ __forceinline__ void ld4<__hip_bfloat16>(const __hip_bfloat16* p, float* o) {
  ushort4 v = *reinterpret_cast<const ushort4*>(p);
  union { unsigned u; float f; } t;
  t.u = (unsigned)v.x << 16; o[0] = t.f;
  t.u = (unsigned)v.y << 16; o[1] = t.f;
  t.u = (unsigned)v.z << 16; o[2] = t.f;
  t.u = (unsigned)v.w << 16; o[3] = t.f;
}

// block reduce over nw waves (blockDim = nw*64); all threads must call
__device__ __forceinline__ float bsum(float v, float* red, int nw) {
#pragma unroll
  for (int off = 32; off > 0; off >>= 1) v += __shfl_down(v, off);
  int lane = threadIdx.x & 63, wid = threadIdx.x >> 6;
  __syncthreads();
  if (lane == 0) red[wid] = v;
  __syncthreads();
  float s = 0.f;
  for (int i = 0; i < nw; i++) s += red[i];
  return s;
}

// ---------------------------------------------------------------------------
// Kernel A: per-feature GRU scan.
// Block = (f, 4-batch chunk), 384 threads.
// Thread (gq = tid%96, ks = tid/96) owns rows 4gq..4gq+3, k-slice [32ks,32ks+32)
// of Whh[f] in 128 VGPRs. h lives in LDS (fp32 master). Partials reduced in LDS.
// ---------------------------------------------------------------------------
template <typename ST>
__global__ __launch_bounds__(384, 3) void gru_scan(
    const float* __restrict__ x, const float* __restrict__ Wih,
    const float* __restrict__ Whh, const float* __restrict__ bih,
    const float* __restrict__ bhh, ST* __restrict__ Hs, float* __restrict__ hT) {
  const int f = blockIdx.x;
  const int b0 = blockIdx.y * BCH;
  const int tid = threadIdx.x;
  const int gq = tid % 96;   // row quad
  const int ks = tid / 96;   // k-slice 0..3
  const int g0 = gq * 4;

  float w[4][32];
#pragma unroll
  for (int j = 0; j < 4; j++) {
    const float* wr = Whh + ((size_t)f * H3c + (g0 + j)) * Hc + ks * 32;
#pragma unroll
    for (int kk = 0; kk < 32; kk += 4) {
      float4 v = *reinterpret_cast<const float4*>(wr + kk);
      w[j][kk] = v.x; w[j][kk + 1] = v.y; w[j][kk + 2] = v.z; w[j][kk + 3] = v.w;
    }
  }

  float wih0 = 0, wih1 = 0, wih2 = 0, bih0 = 0, bih1 = 0, bih2 = 0;
  float bhh0 = 0, bhh1 = 0, bhh2 = 0;
  if (tid < Hc) {
    wih0 = Wih[f * H3c + tid];          bih0 = bih[f * H3c + tid];          bhh0 = bhh[f * H3c + tid];
    wih1 = Wih[f * H3c + Hc + tid];     bih1 = bih[f * H3c + Hc + tid];     bhh1 = bhh[f * H3c + Hc + tid];
    wih2 = Wih[f * H3c + 2 * Hc + tid]; bih2 = bih[f * H3c + 2 * Hc + tid]; bhh2 = bhh[f * H3c + 2 * Hc + tid];
  }

  __shared__ __align__(16) float hs[BCH][Hc];
  __shared__ __align__(16) float part[BCH][4][H3c];
  for (int i = tid; i < BCH * Hc; i += 384) (&hs[0][0])[i] = 0.f;
  __syncthreads();

  for (int t = 0; t < Tc; t++) {
    // phase 1: partial matvec for 4 rows x 32-k slice x BCH batches
#pragma unroll
    for (int b = 0; b < BCH; b++) {
      float a0 = 0, a1 = 0, a2 = 0, a3 = 0;
#pragma unroll
      for (int kk = 0; kk < 32; kk += 4) {
        float4 hv = *reinterpret_cast<const float4*>(&hs[b][ks * 32 + kk]);
        a0 += w[0][kk] * hv.x + w[0][kk + 1] * hv.y + w[0][kk + 2] * hv.z + w[0][kk + 3] * hv.w;
        a1 += w[1][kk] * hv.x + w[1][kk + 1] * hv.y + w[1][kk + 2] * hv.z + w[1][kk + 3] * hv.w;
        a2 += w[2][kk] * hv.x + w[2][kk + 1] * hv.y + w[2][kk + 2] * hv.z + w[2][kk + 3] * hv.w;
        a3 += w[3][kk] * hv.x + w[3][kk + 1] * hv.y + w[3][kk + 2] * hv.z + w[3][kk + 3] * hv.w;
      }
      *reinterpret_cast<float4*>(&part[b][ks][g0]) = make_float4(a0, a1, a2, a3);
    }
    __syncthreads();
    // phase 2: reduce partials, gates, h update (threads 0..127 = hidden idx)
    if (tid < Hc) {
#pragma unroll
      for (int b = 0; b < BCH; b++) {
        float xv = x[((size_t)(b0 + b) * Tc + t) * Fc + f];
        float ghr = part[b][0][tid] + part[b][1][tid] + part[b][2][tid] + part[b][3][tid] + bhh0;
        float ghz = part[b][0][Hc + tid] + part[b][1][Hc + tid] + part[b][2][Hc + tid] + part[b][3][Hc + tid] + bhh1;
        float ghn = part[b][0][2 * Hc + tid] + part[b][1][2 * Hc + tid] + part[b][2][2 * Hc + tid] + part[b][3][2 * Hc + tid] + bhh2;
        float r = sigf(xv * wih0 + bih0 + ghr);
        float z = sigf(xv * wih1 + bih1 + ghz);
        float n = tanhf(xv * wih2 + bih2 + r * ghn);
        float hnew = (1.f - z) * n + z * hs[b][tid];
        hs[b][tid] = hnew;
        stv(&Hs[(((size_t)(b0 + b) * Tc + t) * Fc + f) * Hc + tid], hnew);
      }
    }
    __syncthreads();
  }
  if (tid < Hc) {
#pragma unroll
    for (int b = 0; b < BCH; b++)
      hT[((size_t)(b0 + b) * Fc + f) * Hc + tid] = hs[b][tid];
  }
}

// ---------------------------------------------------------------------------
// Kernel B: time-aware per-feature attention. Block per (f,b), 256 threads.
// ---------------------------------------------------------------------------
template <typename ST>
__global__ __launch_bounds__(256) void feat_attn(
    const ST* __restrict__ Hs, const float* __restrict__ hT,
    const float* __restrict__ Wt, const float* __restrict__ Wx,
    const float* __restrict__ rate, float* __restrict__ posi) {
  const int f = blockIdx.x, b = blockIdx.y;
  const int tid = threadIdx.x;
  __shared__ float tile[Tc][Hc + 1];
  __shared__ float wxs[Hc][Ac];
  __shared__ float qs[Ac];
  __shared__ float es[Tc];
  __shared__ float red[2];

  for (int i = tid; i < Tc * (Hc / 4); i += 256) {
    int t = i >> 5, k = (i & 31) << 2;
    float o[4];
    ld4(&Hs[(((size_t)b * Tc + t) * Fc + f) * Hc + k], o);
    tile[t][k] = o[0]; tile[t][k + 1] = o[1]; tile[t][k + 2] = o[2]; tile[t][k + 3] = o[3];
  }
  for (int i = tid; i < Hc * Ac; i += 256) (&wxs[0][0])[i] = Wx[(size_t)f * Hc * Ac + i];
  if (tid < Ac) {
    float q = 0.f;
    const float* hTp = hT + ((size_t)b * Fc + f) * Hc;
    for (int h = 0; h < Hc; h++) q += hTp[h] * Wt[((size_t)f * Hc + h) * Ac + tid];
    qs[tid] = q;
  }
  __syncthreads();
  if (tid < Tc) {
    float ka[Ac];
#pragma unroll
    for (int a = 0; a < Ac; a++) ka[a] = 0.f;
    for (int h = 0; h < Hc; h++) {
      float hv = tile[tid][h];
#pragma unroll
      for (int a = 0; a < Ac; a++) ka[a] += hv * wxs[h][a];
    }
    float dot = 0.f;
#pragma unroll
    for (int a = 0; a < Ac; a++) dot += qs[a] * ka[a];
    float sd = sigf(dot);
    float denom = sigf(rate[f]) * (logf(2.72f + (1.f - sd)) * (float)(Tc - tid));
    es[tid] = fmaxf(sd / denom, 0.f);
  }
  __syncthreads();
  if (tid == 0) {
    float m = -1e30f;
    for (int t = 0; t < Tc; t++) m = fmaxf(m, es[t]);
    red[0] = m;
  }
  __syncthreads();
  if (tid < Tc) es[tid] = expf(es[tid] - red[0]);
  __syncthreads();
  if (tid == 0) {
    float s = 0.f;
    for (int t = 0; t < Tc; t++) s += es[t];
    red[1] = 1.f / s;
  }
  __syncthreads();
  if (tid < Hc) {
    float acc = 0.f;
    for (int t = 0; t < Tc; t++) acc += es[t] * tile[t][tid];
    posi[((size_t)b * Nc + f) * Hc + tid] = acc * red[1];
  }
}

// ---------------------------------------------------------------------------
__global__ __launch_bounds__(128) void demo_k(
    const float* __restrict__ demo, const float* __restrict__ dW,
    const float* __restrict__ db, float* __restrict__ posi) {
  int b = blockIdx.x, h = threadIdx.x;
  float acc = db[h];
  const float* dp = demo + b * DEMOc;
  const float* wp = dW + h * DEMOc;
#pragma unroll
  for (int d = 0; d < DEMOc; d++) acc += dp[d] * wp[d];
  posi[((size_t)b * Nc + (Nc - 1)) * Hc + h] = tanhf(acc);
}

__global__ __launch_bounds__(128) void ln_qkv(
    const float* __restrict__ posi, const float* __restrict__ ga, const float* __restrict__ be,
    const float* __restrict__ Wq, const float* __restrict__ bq,
    const float* __restrict__ Wk, const float* __restrict__ bk,
    const float* __restrict__ Wv, const float* __restrict__ bv,
    float* __restrict__ qb, float* __restrict__ kb, float* __restrict__ vb) {
  int bn = blockIdx.x;
  int b = bn / Nc, n = bn % Nc;
  int h = threadIdx.x;
  __shared__ float xn[Hc];
  __shared__ float red[2];
  float xv = posi[(size_t)bn * Hc + h];
  float m = bsum(xv, red, 2) * (1.f / Hc);
  float d = xv - m;
  float var = bsum(d * d, red, 2) * (1.f / (Hc - 1));
  xn[h] = ga[h] * d / (sqrtf(var) + 1e-7f) + be[h];
  __syncthreads();
  float q = bq[h], k = bk[h], v = bv[h];
  for (int kk = 0; kk < Hc; kk++) {
    float xk = xn[kk];
    q += xk * Wq[h * Hc + kk];
    k += xk * Wk[h * Hc + kk];
    v += xk * Wv[h * Hc + kk];
  }
  int head = h >> 5, dd = h & 31;
  size_t o = (((size_t)b * NHc + head) * Nc + n) * DKc + dd;
  qb[o] = q; kb[o] = k; vb[o] = v;
}

__global__ __launch_bounds__(64) void mha_attn(
    const float* __restrict__ qb, const float* __restrict__ kb,
    const float* __restrict__ vb, float* __restrict__ ctx) {
  int hd = blockIdx.x, b = blockIdx.y;
  int tid = threadIdx.x;
  __shared__ float ksm[Nc][DKc];
  __shared__ float vsm[Nc][DKc];
  __shared__ float sc[Nc][Nc];
  size_t base = ((size_t)b * NHc + hd) * Nc * DKc;
  for (int i = tid; i < Nc * DKc; i += 64) {
    ksm[i / DKc][i % DKc] = kb[base + i];
    vsm[i / DKc][i % DKc] = vb[base + i];
  }
  __syncthreads();
  if (tid < Nc) {
    float qr[DKc];
#pragma unroll
    for (int d = 0; d < DKc; d++) qr[d] = qb[base + tid * DKc + d];
    float mx = -1e30f;
    for (int mm = 0; mm < Nc; mm++) {
      float s = 0.f;
#pragma unroll
      for (int d = 0; d < DKc; d++) s += qr[d] * ksm[mm][d];
      s *= 0.17677669529663687f;  // 1/sqrt(32)
      sc[tid][mm] = s;
      mx = fmaxf(mx, s);
    }
    float ssum = 0.f;
    for (int mm = 0; mm < Nc; mm++) {
      float e = expf(sc[tid][mm] - mx);
      sc[tid][mm] = e;
      ssum += e;
    }
    float inv = 1.f / ssum;
    float acc[DKc];
#pragma unroll
    for (int d = 0; d < DKc; d++) acc[d] = 0.f;
    for (int mm = 0; mm < Nc; mm++) {
      float p = sc[tid][mm] * inv;
#pragma unroll
      for (int d = 0; d < DKc; d++) acc[d] += p * vsm[mm][d];
    }
    float* cp = ctx + ((size_t)b * Nc + tid) * Hc + hd * DKc;
#pragma unroll
    for (int d = 0; d < DKc; d++) cp[d] = acc[d];
  }
}

__global__ __launch_bounds__(128) void wo_res(
    const float* __restrict__ ctx, const float* __restrict__ Wo,
    const float* __restrict__ bo, const float* __restrict__ posi,
    float* __restrict__ mha, float* __restrict__ h1) {
  int bn = blockIdx.x;
  int h = threadIdx.x;
  __shared__ float cs[Hc];
  cs[h] = ctx[(size_t)bn * Hc + h];
  __syncthreads();
  float acc = bo[h];
  for (int k = 0; k < Hc; k++) acc += cs[k] * Wo[h * Hc + k];
  mha[(size_t)bn * Hc + h] = acc;
  h1[(size_t)bn * Hc + h] = posi[(size_t)bn * Hc + h] + acc;
}

__global__ __launch_bounds__(256) void decov_k(
    const float* __restrict__ mha, float* __restrict__ dacc) {
  int n = blockIdx.x;
  int tid = threadIdx.x;
  __shared__ float xc[Bc][Hc];
  __shared__ float red[4];
  for (int i = tid; i < Bc * Hc; i += 256) {
    int b = i >> 7, h = i & 127;
    xc[b][h] = mha[((size_t)b * Nc + n) * Hc + h];
  }
  __syncthreads();
  if (tid < Hc) {
    float s = 0.f;
    for (int b = 0; b < Bc; b++) s += xc[b][tid];
    s *= (1.f / Bc);
    for (int b = 0; b < Bc; b++) xc[b][tid] -= s;
  }
  __syncthreads();
  float p2 = 0.f, pd = 0.f;
  for (int e = tid; e < Hc * Hc; e += 256) {
    int hh = e >> 7, gg = e & 127;
    float c = 0.f;
    for (int b = 0; b < Bc; b++) c += xc[b][hh] * xc[b][gg];
    c *= (1.f / (Bc - 1));
    float c2 = c * c;
    p2 += c2;
    if (hh == gg) pd += c2;
  }
  float s2 = bsum(p2, red, 4);
  float sdg = bsum(pd, red, 4);
  if (tid == 0) atomicAdd(dacc, 0.5f * (s2 - sdg));
}

__global__ __launch_bounds__(256) void ln2_ffn1(
    const float* __restrict__ h1, const float* __restrict__ ga, const float* __restrict__ be,
    const float* __restrict__ W1, const float* __restrict__ b1, float* __restrict__ t1) {
  int bn = blockIdx.x;
  int tid = threadIdx.x;
  __shared__ float xn[Hc];
  __shared__ float red[4];
  float xv = (tid < Hc) ? h1[(size_t)bn * Hc + tid] : 0.f;
  float m = bsum(xv, red, 4) * (1.f / Hc);
  float d = (tid < Hc) ? (xv - m) : 0.f;
  float var = bsum(d * d, red, 4) * (1.f / (Hc - 1));
  if (tid < Hc) xn[tid] = ga[tid] * d / (sqrtf(var) + 1e-7f) + be[tid];
  __syncthreads();
#pragma unroll
  for (int jj = 0; jj < 2; jj++) {
    int j = tid + jj * 256;
    float acc = b1[j];
    for (int k = 0; k < Hc; k++) acc += xn[k] * W1[j * Hc + k];
    t1[(size_t)bn * DFFc + j] = fmaxf(acc, 0.f);
  }
}

__global__ __launch_bounds__(128) void ffn2_res(
    const float* __restrict__ t1, const float* __restrict__ W2,
    const float* __restrict__ b2, const float* __restrict__ h1, float* __restrict__ h2) {
  int bn = blockIdx.x;
  int h = threadIdx.x;
  __shared__ float ts[DFFc];
  for (int i = h; i < DFFc; i += 128) ts[i] = t1[(size_t)bn * DFFc + i];
  __syncthreads();
  float acc = b2[h];
  for (int j = 0; j < DFFc; j++) acc += ts[j] * W2[h * DFFc + j];
  h2[(size_t)bn * Hc + h] = h1[(size_t)bn * Hc + h] + acc;
}

__global__ __launch_bounds__(128) void final_k(
    const float* __restrict__ h2,
    const float* __restrict__ Wq, const float* __restrict__ bq,
    const float* __restrict__ Wk, const float* __restrict__ bk,
    const float* __restrict__ Wv, const float* __restrict__ bv,
    const float* __restrict__ oW, const float* __restrict__ ob,
    const float* __restrict__ dacc, float* __restrict__ out) {
  int b = blockIdx.x, h = threadIdx.x;
  __shared__ float h2s[Nc][Hc];
  __shared__ float fks[Nc][Hc + 1];
  __shared__ float fqs[Hc];
  __shared__ float alphas[Nc];
  __shared__ float red[2];
  __shared__ float r2[2];
  for (int i = h; i < Nc * Hc; i += 128) h2s[i / Hc][i % Hc] = h2[(size_t)b * Nc * Hc + i];
  __syncthreads();
  {
    float q = bq[h];
    for (int k = 0; k < Hc; k++) q += h2s[Nc - 1][k] * Wq[h * Hc + k];
    fqs[h] = q;
  }
  for (int n = 0; n < Nc; n++) {
    float fk = bk[h];
    for (int k = 0; k < Hc; k++) fk += h2s[n][k] * Wk[h * Hc + k];
    fks[n][h] = fk;
  }
  __syncthreads();
  if (h < Nc) {
    float fe = 0.f;
    for (int k = 0; k < Hc; k++) fe += fks[h][k] * fqs[k];
    alphas[h] = fe;
  }
  __syncthreads();
  if (h == 0) {
    float m = -1e30f;
    for (int n = 0; n < Nc; n++) m = fmaxf(m, alphas[n]);
    float s = 0.f;
    for (int n = 0; n < Nc; n++) {
      float e = expf(alphas[n] - m);
      alphas[n] = e;
      s += e;
    }
    red[0] = 1.f / s;
  }
  __syncthreads();
  float inv = red[0];
  float pv = 0.f;
  for (int n = 0; n < Nc; n++) {
    float fv = bv[h];
    for (int k = 0; k < Hc; k++) fv += h2s[n][k] * Wv[h * Hc + k];
    pv += alphas[n] * fv;
  }
  pv *= inv;
  float c = pv * oW[h];
#pragma unroll
  for (int off = 32; off > 0; off >>= 1) c += __shfl_down(c, off);
  int lane = h & 63, wid = h >> 6;
  if (lane == 0) r2[wid] = c;
  __syncthreads();
  if (h == 0) {
    out[b] = sigf(r2[0] + r2[1] + ob[0]);
    if (b == 0) out[Bc] = dacc[0];
  }
}

}  // namespace

extern "C" void kernel_launch(void* const* d_in, const int* in_sizes, int n_in,
                              void* d_out, int out_size, void* d_ws, size_t ws_size,
                              hipStream_t stream) {
  const float* x    = (const float*)d_in[0];
  const float* demo = (const float*)d_in[1];
  const float* gWih = (const float*)d_in[2];
  const float* gWhh = (const float*)d_in[3];
  const float* gbih = (const float*)d_in[4];
  const float* gbhh = (const float*)d_in[5];
  const float* aWt  = (const float*)d_in[6];
  const float* aWx  = (const float*)d_in[7];
  const float* aRt  = (const float*)d_in[8];
  const float* dW   = (const float*)d_in[9];
  const float* db   = (const float*)d_in[10];
  const float* mWq  = (const float*)d_in[11];
  const float* mbq  = (const float*)d_in[12];
  const float* mWk  = (const float*)d_in[13];
  const float* mbk  = (const float*)d_in[14];
  const float* mWv  = (const float*)d_in[15];
  const float* mbv  = (const float*)d_in[16];
  const float* mWo  = (const float*)d_in[17];
  const float* mbo  = (const float*)d_in[18];
  const float* l1a  = (const float*)d_in[19];
  const float* l1b  = (const float*)d_in[20];
  const float* l2a  = (const float*)d_in[21];
  const float* l2b  = (const float*)d_in[22];
  const float* fW1  = (const float*)d_in[23];
  const float* fb1  = (const float*)d_in[24];
  const float* fW2  = (const float*)d_in[25];
  const float* fb2  = (const float*)d_in[26];
  const float* fWq  = (const float*)d_in[27];
  const float* fbq  = (const float*)d_in[28];
  const float* fWk  = (const float*)d_in[29];
  const float* fbk  = (const float*)d_in[30];
  const float* fWv  = (const float*)d_in[31];
  const float* fbv  = (const float*)d_in[32];
  const float* oW   = (const float*)d_in[33];
  const float* ob   = (const float*)d_in[34];

  char* base = (char*)d_ws;
  size_t off = 0;
  auto take = [&](size_t nfloats) -> float* {
    float* r = (float*)(base + off);
    off += ((nfloats * sizeof(float)) + 255) & ~(size_t)255;
    return r;
  };
  float* dec  = take(64);
  float* hT   = take((size_t)Bc * Fc * Hc);
  float* posi = take((size_t)Bc * Nc * Hc);
  float* qb   = take((size_t)Bc * Nc * Hc);
  float* kb   = take((size_t)Bc * Nc * Hc);
  float* vb   = take((size_t)Bc * Nc * Hc);
  float* ctx  = take((size_t)Bc * Nc * Hc);
  float* mha  = take((size_t)Bc * Nc * Hc);
  float* h1   = take((size_t)Bc * Nc * Hc);
  float* t1   = take((size_t)Bc * Nc * DFFc);
  float* h2   = take((size_t)Bc * Nc * Hc);
  size_t HsElems = (size_t)Bc * Tc * Fc * Hc;  // 37.7M
  void* HsPtr = (void*)(base + off);
  bool f32path = (ws_size >= off + HsElems * sizeof(float));

  hipMemsetAsync(dec, 0, sizeof(float), stream);

  dim3 gGru(Fc, Bc / BCH);
  dim3 gAtt(Fc, Bc);
  if (f32path) {
    gru_scan<float><<<gGru, 384, 0, stream>>>(x, gWih, gWhh, gbih, gbhh, (float*)HsPtr, hT);
    feat_attn<float><<<gAtt, 256, 0, stream>>>((const float*)HsPtr, hT, aWt, aWx, aRt, posi);
  } else {
    gru_scan<__hip_bfloat16><<<gGru, 384, 0, stream>>>(x, gWih, gWhh, gbih, gbhh,
                                                       (__hip_bfloat16*)HsPtr, hT);
    feat_attn<__hip_bfloat16><<<gAtt, 256, 0, stream>>>((const __hip_bfloat16*)HsPtr, hT,
                                                        aWt, aWx, aRt, posi);
  }
  demo_k<<<Bc, 128, 0, stream>>>(demo, dW, db, posi);
  ln_qkv<<<Bc * Nc, 128, 0, stream>>>(posi, l1a, l1b, mWq, mbq, mWk, mbk, mWv, mbv, qb, kb, vb);
  mha_attn<<<dim3(NHc, Bc), 64, 0, stream>>>(qb, kb, vb, ctx);
  wo_res<<<Bc * Nc, 128, 0, stream>>>(ctx, mWo, mbo, posi, mha, h1);
  decov_k<<<Nc, 256, 0, stream>>>(mha, dec);
  ln2_ffn1<<<Bc * Nc, 256, 0, stream>>>(h1, l2a, l2b, fW1, fb1, t1);
  ffn2_res<<<Bc * Nc, 128, 0, stream>>>(t1, fW2, fb2, h1, h2);
  final_k<<<Bc, 128, 0, stream>>>(h2, fWq, fbq, fWk, fbk, fWv, fbv, oW, ob, dec, (float*)d_out);
}

// Round 4
// 1863.677 us; speedup vs baseline: 2.9376x; 2.9376x over previous
//
#include <hip/hip_runtime.h>
#include <hip/hip_bf16.h>

namespace {

constexpr int Bc = 64, Tc = 96, Fc = 48, Hc = 128, Ac = 8;
constexpr int DFFc = 512, DEMOc = 12, NHc = 4, Nc = 49, H3c = 384, DKc = 32;
constexpr int BCH = 4;  // batches per GRU block

__device__ __forceinline__ float sigf(float x) { return 1.f / (1.f + expf(-x)); }

template <typename ST> __device__ __forceinline__ void stv(ST* p, float v);
template <> __device__ __forceinline__ void stv<float>(float* p, float v) { *p = v; }
template <> __device__ __forceinline__ void stv<__hip_bfloat16>(__hip_bfloat16* p, float v) {
  *p = __float2bfloat16(v);
}

template <typename ST> __device__ __forceinline__ void ld4(const ST* p, float* o);
template <> __device__ __forceinline__ void ld4<float>(const float* p, float* o) {
  float4 v = *reinterpret_cast<const float4*>(p);
  o[0] = v.x; o[1] = v.y; o[2] = v.z; o[3] = v.w;
}
template <> __device__ __forceinline__ void ld4<__hip_bfloat16>(const __hip_bfloat16* p, float* o) {
  ushort4 v = *reinterpret_cast<const ushort4*>(p);
  union { unsigned u; float f; } t;
  t.u = (unsigned)v.x << 16; o[0] = t.f;
  t.u = (unsigned)v.y << 16; o[1] = t.f;
  t.u = (unsigned)v.z << 16; o[2] = t.f;
  t.u = (unsigned)v.w << 16; o[3] = t.f;
}

// block reduce over nw waves (blockDim = nw*64); all threads must call
__device__ __forceinline__ float bsum(float v, float* red, int nw) {
#pragma unroll
  for (int off = 32; off > 0; off >>= 1) v += __shfl_down(v, off);
  int lane = threadIdx.x & 63, wid = threadIdx.x >> 6;
  __syncthreads();
  if (lane == 0) red[wid] = v;
  __syncthreads();
  float s = 0.f;
  for (int i = 0; i < nw; i++) s += red[i];
  return s;
}

// ---------------------------------------------------------------------------
// Kernel A: per-feature GRU scan.
// Block = (f, 4-batch chunk), 384 threads.
// Thread (gq = tid%96, ks = tid/96) owns rows 4gq..4gq+3, k-slice [32ks,32ks+32)
// of Whh[f] in 128 VGPRs. h lives in LDS (fp32 master). Partials reduced in LDS.
// launch_bounds min-waves=2 (VGPR cap 256): min-waves=3 (cap 170) made the
// compiler SPILL the 128-float w array to scratch -> 11.3 GB HBM fetch/dispatch
// (measured r2: VGPR_Count=84, FETCH 1.13e7 KB, dur 4820 us). Keep w resident.
// ---------------------------------------------------------------------------
template <typename ST>
__global__ __launch_bounds__(384, 2) void gru_scan(
    const float* __restrict__ x, const float* __restrict__ Wih,
    const float* __restrict__ Whh, const float* __restrict__ bih,
    const float* __restrict__ bhh, ST* __restrict__ Hs, float* __restrict__ hT) {
  const int f = blockIdx.x;
  const int b0 = blockIdx.y * BCH;
  const int tid = threadIdx.x;
  const int gq = tid % 96;   // row quad
  const int ks = tid / 96;   // k-slice 0..3
  const int g0 = gq * 4;

  float w[4][32];
#pragma unroll
  for (int j = 0; j < 4; j++) {
    const float* wr = Whh + ((size_t)f * H3c + (g0 + j)) * Hc + ks * 32;
#pragma unroll
    for (int kk = 0; kk < 32; kk += 4) {
      float4 v = *reinterpret_cast<const float4*>(wr + kk);
      w[j][kk] = v.x; w[j][kk + 1] = v.y; w[j][kk + 2] = v.z; w[j][kk + 3] = v.w;
    }
  }

  float wih0 = 0, wih1 = 0, wih2 = 0, bih0 = 0, bih1 = 0, bih2 = 0;
  float bhh0 = 0, bhh1 = 0, bhh2 = 0;
  if (tid < Hc) {
    wih0 = Wih[f * H3c + tid];          bih0 = bih[f * H3c + tid];          bhh0 = bhh[f * H3c + tid];
    wih1 = Wih[f * H3c + Hc + tid];     bih1 = bih[f * H3c + Hc + tid];     bhh1 = bhh[f * H3c + Hc + tid];
    wih2 = Wih[f * H3c + 2 * Hc + tid]; bih2 = bih[f * H3c + 2 * Hc + tid]; bhh2 = bhh[f * H3c + 2 * Hc + tid];
  }

  __shared__ __align__(16) float hs[BCH][Hc];
  __shared__ __align__(16) float part[BCH][4][H3c];
  for (int i = tid; i < BCH * Hc; i += 384) (&hs[0][0])[i] = 0.f;
  __syncthreads();

  for (int t = 0; t < Tc; t++) {
    // phase 1: partial matvec for 4 rows x 32-k slice x BCH batches
#pragma unroll
    for (int b = 0; b < BCH; b++) {
      float a0 = 0, a1 = 0, a2 = 0, a3 = 0;
#pragma unroll
      for (int kk = 0; kk < 32; kk += 4) {
        float4 hv = *reinterpret_cast<const float4*>(&hs[b][ks * 32 + kk]);
        a0 += w[0][kk] * hv.x + w[0][kk + 1] * hv.y + w[0][kk + 2] * hv.z + w[0][kk + 3] * hv.w;
        a1 += w[1][kk] * hv.x + w[1][kk + 1] * hv.y + w[1][kk + 2] * hv.z + w[1][kk + 3] * hv.w;
        a2 += w[2][kk] * hv.x + w[2][kk + 1] * hv.y + w[2][kk + 2] * hv.z + w[2][kk + 3] * hv.w;
        a3 += w[3][kk] * hv.x + w[3][kk + 1] * hv.y + w[3][kk + 2] * hv.z + w[3][kk + 3] * hv.w;
      }
      *reinterpret_cast<float4*>(&part[b][ks][g0]) = make_float4(a0, a1, a2, a3);
    }
    __syncthreads();
    // phase 2: reduce partials, gates, h update (threads 0..127 = hidden idx)
    if (tid < Hc) {
#pragma unroll
      for (int b = 0; b < BCH; b++) {
        float xv = x[((size_t)(b0 + b) * Tc + t) * Fc + f];
        float ghr = part[b][0][tid] + part[b][1][tid] + part[b][2][tid] + part[b][3][tid] + bhh0;
        float ghz = part[b][0][Hc + tid] + part[b][1][Hc + tid] + part[b][2][Hc + tid] + part[b][3][Hc + tid] + bhh1;
        float ghn = part[b][0][2 * Hc + tid] + part[b][1][2 * Hc + tid] + part[b][2][2 * Hc + tid] + part[b][3][2 * Hc + tid] + bhh2;
        float r = sigf(xv * wih0 + bih0 + ghr);
        float z = sigf(xv * wih1 + bih1 + ghz);
        float n = tanhf(xv * wih2 + bih2 + r * ghn);
        float hnew = (1.f - z) * n + z * hs[b][tid];
        hs[b][tid] = hnew;
        stv(&Hs[(((size_t)(b0 + b) * Tc + t) * Fc + f) * Hc + tid], hnew);
      }
    }
    __syncthreads();
  }
  if (tid < Hc) {
#pragma unroll
    for (int b = 0; b < BCH; b++)
      hT[((size_t)(b0 + b) * Fc + f) * Hc + tid] = hs[b][tid];
  }
}

// ---------------------------------------------------------------------------
// Kernel B: time-aware per-feature attention. Block per (f,b), 256 threads.
// ---------------------------------------------------------------------------
template <typename ST>
__global__ __launch_bounds__(256) void feat_attn(
    const ST* __restrict__ Hs, const float* __restrict__ hT,
    const float* __restrict__ Wt, const float* __restrict__ Wx,
    const float* __restrict__ rate, float* __restrict__ posi) {
  const int f = blockIdx.x, b = blockIdx.y;
  const int tid = threadIdx.x;
  __shared__ float tile[Tc][Hc + 1];
  __shared__ float wxs[Hc][Ac];
  __shared__ float qs[Ac];
  __shared__ float es[Tc];
  __shared__ float red[2];

  for (int i = tid; i < Tc * (Hc / 4); i += 256) {
    int t = i >> 5, k = (i & 31) << 2;
    float o[4];
    ld4(&Hs[(((size_t)b * Tc + t) * Fc + f) * Hc + k], o);
    tile[t][k] = o[0]; tile[t][k + 1] = o[1]; tile[t][k + 2] = o[2]; tile[t][k + 3] = o[3];
  }
  for (int i = tid; i < Hc * Ac; i += 256) (&wxs[0][0])[i] = Wx[(size_t)f * Hc * Ac + i];
  if (tid < Ac) {
    float q = 0.f;
    const float* hTp = hT + ((size_t)b * Fc + f) * Hc;
    for (int h = 0; h < Hc; h++) q += hTp[h] * Wt[((size_t)f * Hc + h) * Ac + tid];
    qs[tid] = q;
  }
  __syncthreads();
  if (tid < Tc) {
    float ka[Ac];
#pragma unroll
    for (int a = 0; a < Ac; a++) ka[a] = 0.f;
    for (int h = 0; h < Hc; h++) {
      float hv = tile[tid][h];
#pragma unroll
      for (int a = 0; a < Ac; a++) ka[a] += hv * wxs[h][a];
    }
    float dot = 0.f;
#pragma unroll
    for (int a = 0; a < Ac; a++) dot += qs[a] * ka[a];
    float sd = sigf(dot);
    float denom = sigf(rate[f]) * (logf(2.72f + (1.f - sd)) * (float)(Tc - tid));
    es[tid] = fmaxf(sd / denom, 0.f);
  }
  __syncthreads();
  if (tid == 0) {
    float m = -1e30f;
    for (int t = 0; t < Tc; t++) m = fmaxf(m, es[t]);
    red[0] = m;
  }
  __syncthreads();
  if (tid < Tc) es[tid] = expf(es[tid] - red[0]);
  __syncthreads();
  if (tid == 0) {
    float s = 0.f;
    for (int t = 0; t < Tc; t++) s += es[t];
    red[1] = 1.f / s;
  }
  __syncthreads();
  if (tid < Hc) {
    float acc = 0.f;
    for (int t = 0; t < Tc; t++) acc += es[t] * tile[t][tid];
    posi[((size_t)b * Nc + f) * Hc + tid] = acc * red[1];
  }
}

// ---------------------------------------------------------------------------
__global__ __launch_bounds__(128) void demo_k(
    const float* __restrict__ demo, const float* __restrict__ dW,
    const float* __restrict__ db, float* __restrict__ posi) {
  int b = blockIdx.x, h = threadIdx.x;
  float acc = db[h];
  const float* dp = demo + b * DEMOc;
  const float* wp = dW + h * DEMOc;
#pragma unroll
  for (int d = 0; d < DEMOc; d++) acc += dp[d] * wp[d];
  posi[((size_t)b * Nc + (Nc - 1)) * Hc + h] = tanhf(acc);
}

__global__ __launch_bounds__(128) void ln_qkv(
    const float* __restrict__ posi, const float* __restrict__ ga, const float* __restrict__ be,
    const float* __restrict__ Wq, const float* __restrict__ bq,
    const float* __restrict__ Wk, const float* __restrict__ bk,
    const float* __restrict__ Wv, const float* __restrict__ bv,
    float* __restrict__ qb, float* __restrict__ kb, float* __restrict__ vb) {
  int bn = blockIdx.x;
  int b = bn / Nc, n = bn % Nc;
  int h = threadIdx.x;
  __shared__ float xn[Hc];
  __shared__ float red[2];
  float xv = posi[(size_t)bn * Hc + h];
  float m = bsum(xv, red, 2) * (1.f / Hc);
  float d = xv - m;
  float var = bsum(d * d, red, 2) * (1.f / (Hc - 1));
  xn[h] = ga[h] * d / (sqrtf(var) + 1e-7f) + be[h];
  __syncthreads();
  float q = bq[h], k = bk[h], v = bv[h];
  for (int kk = 0; kk < Hc; kk++) {
    float xk = xn[kk];
    q += xk * Wq[h * Hc + kk];
    k += xk * Wk[h * Hc + kk];
    v += xk * Wv[h * Hc + kk];
  }
  int head = h >> 5, dd = h & 31;
  size_t o = (((size_t)b * NHc + head) * Nc + n) * DKc + dd;
  qb[o] = q; kb[o] = k; vb[o] = v;
}

__global__ __launch_bounds__(64) void mha_attn(
    const float* __restrict__ qb, const float* __restrict__ kb,
    const float* __restrict__ vb, float* __restrict__ ctx) {
  int hd = blockIdx.x, b = blockIdx.y;
  int tid = threadIdx.x;
  __shared__ float ksm[Nc][DKc];
  __shared__ float vsm[Nc][DKc];
  __shared__ float sc[Nc][Nc];
  size_t base = ((size_t)b * NHc + hd) * Nc * DKc;
  for (int i = tid; i < Nc * DKc; i += 64) {
    ksm[i / DKc][i % DKc] = kb[base + i];
    vsm[i / DKc][i % DKc] = vb[base + i];
  }
  __syncthreads();
  if (tid < Nc) {
    float qr[DKc];
#pragma unroll
    for (int d = 0; d < DKc; d++) qr[d] = qb[base + tid * DKc + d];
    float mx = -1e30f;
    for (int mm = 0; mm < Nc; mm++) {
      float s = 0.f;
#pragma unroll
      for (int d = 0; d < DKc; d++) s += qr[d] * ksm[mm][d];
      s *= 0.17677669529663687f;  // 1/sqrt(32)
      sc[tid][mm] = s;
      mx = fmaxf(mx, s);
    }
    float ssum = 0.f;
    for (int mm = 0; mm < Nc; mm++) {
      float e = expf(sc[tid][mm] - mx);
      sc[tid][mm] = e;
      ssum += e;
    }
    float inv = 1.f / ssum;
    float acc[DKc];
#pragma unroll
    for (int d = 0; d < DKc; d++) acc[d] = 0.f;
    for (int mm = 0; mm < Nc; mm++) {
      float p = sc[tid][mm] * inv;
#pragma unroll
      for (int d = 0; d < DKc; d++) acc[d] += p * vsm[mm][d];
    }
    float* cp = ctx + ((size_t)b * Nc + tid) * Hc + hd * DKc;
#pragma unroll
    for (int d = 0; d < DKc; d++) cp[d] = acc[d];
  }
}

__global__ __launch_bounds__(128) void wo_res(
    const float* __restrict__ ctx, const float* __restrict__ Wo,
    const float* __restrict__ bo, const float* __restrict__ posi,
    float* __restrict__ mha, float* __restrict__ h1) {
  int bn = blockIdx.x;
  int h = threadIdx.x;
  __shared__ float cs[Hc];
  cs[h] = ctx[(size_t)bn * Hc + h];
  __syncthreads();
  float acc = bo[h];
  for (int k = 0; k < Hc; k++) acc += cs[k] * Wo[h * Hc + k];
  mha[(size_t)bn * Hc + h] = acc;
  h1[(size_t)bn * Hc + h] = posi[(size_t)bn * Hc + h] + acc;
}

__global__ __launch_bounds__(256) void decov_k(
    const float* __restrict__ mha, float* __restrict__ dacc) {
  int n = blockIdx.x;
  int tid = threadIdx.x;
  __shared__ float xc[Bc][Hc];
  __shared__ float red[4];
  for (int i = tid; i < Bc * Hc; i += 256) {
    int b = i >> 7, h = i & 127;
    xc[b][h] = mha[((size_t)b * Nc + n) * Hc + h];
  }
  __syncthreads();
  if (tid < Hc) {
    float s = 0.f;
    for (int b = 0; b < Bc; b++) s += xc[b][tid];
    s *= (1.f / Bc);
    for (int b = 0; b < Bc; b++) xc[b][tid] -= s;
  }
  __syncthreads();
  float p2 = 0.f, pd = 0.f;
  for (int e = tid; e < Hc * Hc; e += 256) {
    int hh = e >> 7, gg = e & 127;
    float c = 0.f;
    for (int b = 0; b < Bc; b++) c += xc[b][hh] * xc[b][gg];
    c *= (1.f / (Bc - 1));
    float c2 = c * c;
    p2 += c2;
    if (hh == gg) pd += c2;
  }
  float s2 = bsum(p2, red, 4);
  float sdg = bsum(pd, red, 4);
  if (tid == 0) atomicAdd(dacc, 0.5f * (s2 - sdg));
}

__global__ __launch_bounds__(256) void ln2_ffn1(
    const float* __restrict__ h1, const float* __restrict__ ga, const float* __restrict__ be,
    const float* __restrict__ W1, const float* __restrict__ b1, float* __restrict__ t1) {
  int bn = blockIdx.x;
  int tid = threadIdx.x;
  __shared__ float xn[Hc];
  __shared__ float red[4];
  float xv = (tid < Hc) ? h1[(size_t)bn * Hc + tid] : 0.f;
  float m = bsum(xv, red, 4) * (1.f / Hc);
  float d = (tid < Hc) ? (xv - m) : 0.f;
  float var = bsum(d * d, red, 4) * (1.f / (Hc - 1));
  if (tid < Hc) xn[tid] = ga[tid] * d / (sqrtf(var) + 1e-7f) + be[tid];
  __syncthreads();
#pragma unroll
  for (int jj = 0; jj < 2; jj++) {
    int j = tid + jj * 256;
    float acc = b1[j];
    for (int k = 0; k < Hc; k++) acc += xn[k] * W1[j * Hc + k];
    t1[(size_t)bn * DFFc + j] = fmaxf(acc, 0.f);
  }
}

__global__ __launch_bounds__(128) void ffn2_res(
    const float* __restrict__ t1, const float* __restrict__ W2,
    const float* __restrict__ b2, const float* __restrict__ h1, float* __restrict__ h2) {
  int bn = blockIdx.x;
  int h = threadIdx.x;
  __shared__ float ts[DFFc];
  for (int i = h; i < DFFc; i += 128) ts[i] = t1[(size_t)bn * DFFc + i];
  __syncthreads();
  float acc = b2[h];
  for (int j = 0; j < DFFc; j++) acc += ts[j] * W2[h * DFFc + j];
  h2[(size_t)bn * Hc + h] = h1[(size_t)bn * Hc + h] + acc;
}

__global__ __launch_bounds__(128) void final_k(
    const float* __restrict__ h2,
    const float* __restrict__ Wq, const float* __restrict__ bq,
    const float* __restrict__ Wk, const float* __restrict__ bk,
    const float* __restrict__ Wv, const float* __restrict__ bv,
    const float* __restrict__ oW, const float* __restrict__ ob,
    const float* __restrict__ dacc, float* __restrict__ out) {
  int b = blockIdx.x, h = threadIdx.x;
  __shared__ float h2s[Nc][Hc];
  __shared__ float fks[Nc][Hc + 1];
  __shared__ float fqs[Hc];
  __shared__ float alphas[Nc];
  __shared__ float red[2];
  __shared__ float r2[2];
  for (int i = h; i < Nc * Hc; i += 128) h2s[i / Hc][i % Hc] = h2[(size_t)b * Nc * Hc + i];
  __syncthreads();
  {
    float q = bq[h];
    for (int k = 0; k < Hc; k++) q += h2s[Nc - 1][k] * Wq[h * Hc + k];
    fqs[h] = q;
  }
  for (int n = 0; n < Nc; n++) {
    float fk = bk[h];
    for (int k = 0; k < Hc; k++) fk += h2s[n][k] * Wk[h * Hc + k];
    fks[n][h] = fk;
  }
  __syncthreads();
  if (h < Nc) {
    float fe = 0.f;
    for (int k = 0; k < Hc; k++) fe += fks[h][k] * fqs[k];
    alphas[h] = fe;
  }
  __syncthreads();
  if (h == 0) {
    float m = -1e30f;
    for (int n = 0; n < Nc; n++) m = fmaxf(m, alphas[n]);
    float s = 0.f;
    for (int n = 0; n < Nc; n++) {
      float e = expf(alphas[n] - m);
      alphas[n] = e;
      s += e;
    }
    red[0] = 1.f / s;
  }
  __syncthreads();
  float inv = red[0];
  float pv = 0.f;
  for (int n = 0; n < Nc; n++) {
    float fv = bv[h];
    for (int k = 0; k < Hc; k++) fv += h2s[n][k] * Wv[h * Hc + k];
    pv += alphas[n] * fv;
  }
  pv *= inv;
  float c = pv * oW[h];
#pragma unroll
  for (int off = 32; off > 0; off >>= 1) c += __shfl_down(c, off);
  int lane = h & 63, wid = h >> 6;
  if (lane == 0) r2[wid] = c;
  __syncthreads();
  if (h == 0) {
    out[b] = sigf(r2[0] + r2[1] + ob[0]);
    if (b == 0) out[Bc] = dacc[0];
  }
}

}  // namespace

extern "C" void kernel_launch(void* const* d_in, const int* in_sizes, int n_in,
                              void* d_out, int out_size, void* d_ws, size_t ws_size,
                              hipStream_t stream) {
  const float* x    = (const float*)d_in[0];
  const float* demo = (const float*)d_in[1];
  const float* gWih = (const float*)d_in[2];
  const float* gWhh = (const float*)d_in[3];
  const float* gbih = (const float*)d_in[4];
  const float* gbhh = (const float*)d_in[5];
  const float* aWt  = (const float*)d_in[6];
  const float* aWx  = (const float*)d_in[7];
  const float* aRt  = (const float*)d_in[8];
  const float* dW   = (const float*)d_in[9];
  const float* db   = (const float*)d_in[10];
  const float* mWq  = (const float*)d_in[11];
  const float* mbq  = (const float*)d_in[12];
  const float* mWk  = (const float*)d_in[13];
  const float* mbk  = (const float*)d_in[14];
  const float* mWv  = (const float*)d_in[15];
  const float* mbv  = (const float*)d_in[16];
  const float* mWo  = (const float*)d_in[17];
  const float* mbo  = (const float*)d_in[18];
  const float* l1a  = (const float*)d_in[19];
  const float* l1b  = (const float*)d_in[20];
  const float* l2a  = (const float*)d_in[21];
  const float* l2b  = (const float*)d_in[22];
  const float* fW1  = (const float*)d_in[23];
  const float* fb1  = (const float*)d_in[24];
  const float* fW2  = (const float*)d_in[25];
  const float* fb2  = (const float*)d_in[26];
  const float* fWq  = (const float*)d_in[27];
  const float* fbq  = (const float*)d_in[28];
  const float* fWk  = (const float*)d_in[29];
  const float* fbk  = (const float*)d_in[30];
  const float* fWv  = (const float*)d_in[31];
  const float* fbv  = (const float*)d_in[32];
  const float* oW   = (const float*)d_in[33];
  const float* ob   = (const float*)d_in[34];

  char* base = (char*)d_ws;
  size_t off = 0;
  auto take = [&](size_t nfloats) -> float* {
    float* r = (float*)(base + off);
    off += ((nfloats * sizeof(float)) + 255) & ~(size_t)255;
    return r;
  };
  float* dec  = take(64);
  float* hT   = take((size_t)Bc * Fc * Hc);
  float* posi = take((size_t)Bc * Nc * Hc);
  float* qb   = take((size_t)Bc * Nc * Hc);
  float* kb   = take((size_t)Bc * Nc * Hc);
  float* vb   = take((size_t)Bc * Nc * Hc);
  float* ctx  = take((size_t)Bc * Nc * Hc);
  float* mha  = take((size_t)Bc * Nc * Hc);
  float* h1   = take((size_t)Bc * Nc * Hc);
  float* t1   = take((size_t)Bc * Nc * DFFc);
  float* h2   = take((size_t)Bc * Nc * Hc);
  size_t HsElems = (size_t)Bc * Tc * Fc * Hc;  // 37.7M
  void* HsPtr = (void*)(base + off);
  bool f32path = (ws_size >= off + HsElems * sizeof(float));

  hipMemsetAsync(dec, 0, sizeof(float), stream);

  dim3 gGru(Fc, Bc / BCH);
  dim3 gAtt(Fc, Bc);
  if (f32path) {
    gru_scan<float><<<gGru, 384, 0, stream>>>(x, gWih, gWhh, gbih, gbhh, (float*)HsPtr, hT);
    feat_attn<float><<<gAtt, 256, 0, stream>>>((const float*)HsPtr, hT, aWt, aWx, aRt, posi);
  } else {
    gru_scan<__hip_bfloat16><<<gGru, 384, 0, stream>>>(x, gWih, gWhh, gbih, gbhh,
                                                       (__hip_bfloat16*)HsPtr, hT);
    feat_attn<__hip_bfloat16><<<gAtt, 256, 0, stream>>>((const __hip_bfloat16*)HsPtr, hT,
                                                        aWt, aWx, aRt, posi);
  }
  demo_k<<<Bc, 128, 0, stream>>>(demo, dW, db, posi);
  ln_qkv<<<Bc * Nc, 128, 0, stream>>>(posi, l1a, l1b, mWq, mbq, mWk, mbk, mWv, mbv, qb, kb, vb);
  mha_attn<<<dim3(NHc, Bc), 64, 0, stream>>>(qb, kb, vb, ctx);
  wo_res<<<Bc * Nc, 128, 0, stream>>>(ctx, mWo, mbo, posi, mha, h1);
  decov_k<<<Nc, 256, 0, stream>>>(mha, dec);
  ln2_ffn1<<<Bc * Nc, 256, 0, stream>>>(h1, l2a, l2b, fW1, fb1, t1);
  ffn2_res<<<Bc * Nc, 128, 0, stream>>>(t1, fW2, fb2, h1, h2);
  final_k<<<Bc, 128, 0, stream>>>(h2, fWq, fbq, fWk, fbk, fWv, fbv, oW, ob, dec, (float*)d_out);
}

// Round 6
// 894.183 us; speedup vs baseline: 6.1226x; 2.0842x over previous
//
#include <hip/hip_runtime.h>
#include <hip/hip_bf16.h>

namespace {

constexpr int Bc = 64, Tc = 96, Fc = 48, Hc = 128, Ac = 8;
constexpr int DFFc = 512, DEMOc = 12, NHc = 4, Nc = 49, H3c = 384, DKc = 32;

typedef __attribute__((ext_vector_type(8))) short s8v;   // 8 bf16 = 4 VGPR (MFMA A/B frag)
typedef __attribute__((ext_vector_type(4))) float f4v;   // MFMA C/D frag
typedef __attribute__((ext_vector_type(4))) short s4v;

__device__ __forceinline__ float sigf(float x) { return 1.f / (1.f + expf(-x)); }
__device__ __forceinline__ float sigf_fast(float x) { return 1.f / (1.f + __expf(-x)); }
__device__ __forceinline__ float tanhf_fast(float x) {
  float e = __expf(2.f * x);
  return 1.f - 2.f / (e + 1.f);   // +-inf safe: ->1 / ->-1
}

__device__ __forceinline__ unsigned short f2b(float v) {   // fp32 -> bf16 bits (RNE)
  __hip_bfloat16 h = __float2bfloat16(v);
  union { __hip_bfloat16 b; unsigned short u; } c;
  c.b = h;
  return c.u;
}
__device__ __forceinline__ float b2f(unsigned short u) {
  union { unsigned u32; float f; } c;
  c.u32 = (unsigned)u << 16;
  return c.f;
}

template <typename ST> __device__ __forceinline__ void stv(ST* p, float v);
template <> __device__ __forceinline__ void stv<float>(float* p, float v) { *p = v; }
template <> __device__ __forceinline__ void stv<__hip_bfloat16>(__hip_bfloat16* p, float v) {
  *p = __float2bfloat16(v);
}

template <typename ST> __device__ __forceinline__ void ld4(const ST* p, float* o);
template <> __device__ __forceinline__ void ld4<float>(const float* p, float* o) {
  float4 v = *reinterpret_cast<const float4*>(p);
  o[0] = v.x; o[1] = v.y; o[2] = v.z; o[3] = v.w;
}
template <> __device__ __forceinline__ void ld4<__hip_bfloat16>(const __hip_bfloat16* p, float* o) {
  ushort4 v = *reinterpret_cast<const ushort4*>(p);
  union { unsigned u; float f; } t;
  t.u = (unsigned)v.x << 16; o[0] = t.f;
  t.u = (unsigned)v.y << 16; o[1] = t.f;
  t.u = (unsigned)v.z << 16; o[2] = t.f;
  t.u = (unsigned)v.w << 16; o[3] = t.f;
}

// block reduce over nw waves (blockDim = nw*64); all threads must call
__device__ __forceinline__ float bsum(float v, float* red, int nw) {
#pragma unroll
  for (int off = 32; off > 0; off >>= 1) v += __shfl_down(v, off);
  int lane = threadIdx.x & 63, wid = threadIdx.x >> 6;
  __syncthreads();
  if (lane == 0) red[wid] = v;
  __syncthreads();
  float s = 0.f;
  for (int i = 0; i < nw; i++) s += red[i];
  return s;
}

// ---------------------------------------------------------------------------
// GRU scan via MFMA (r5 rewrite).
// History: r2 (fp32 weights-in-VGPR, launch_bounds(384,3)): compiler spilled ->
// 11.3 GB HBM scratch traffic, 4820 us. r4 (cap 256): VGPR_Count=96 -> compiler
// STILL refused to promote the 128-float array; weights re-read from L2 every
// step, 1130 us, VALUBusy 30%. Lesson: don't fight the allocator with fp32
// arrays; use MFMA with small bf16 frags (m97-style ext-vector regs).
//
// Block = (f, 16-batch chunk), 512 thr = 8 waves, grid 48x4.
// Per t: gh[16b,384g] = H[16b,128k] x Whh[f]^T via mfma_f32_16x16x32_bf16.
// Wave w owns h-rows 16w..16w+15 for all 3 gates (r/z/n) -> D frag (col=lane&15,
// row=(lane>>4)*4+reg, m89-verified) puts r,z,n for same (b,h) in the SAME lane:
// gate math fully in-register, no gh LDS. h double-buffered in LDS (1 barrier/t).
// Precision: split bf16 (W = W_hi+W_lo, h = h_hi+h_lo; 3 products, drop lo*lo)
// -> ~2^-16 effective mantissa, fp32 accum.
// LDS h layout XOR-swizzled per 16B granule: idx(row,k) = row*128 +
// (((k>>3) ^ (row&7))<<3) + (k&7)  -> conflict-free ds_read_b128 A-frags.
// ---------------------------------------------------------------------------
template <typename ST>
__global__ __launch_bounds__(512, 2) void gru_mfma(
    const float* __restrict__ x, const float* __restrict__ Wih,
    const float* __restrict__ Whh, const float* __restrict__ bih,
    const float* __restrict__ bhh, ST* __restrict__ Hs, float* __restrict__ hT) {
  const int f = blockIdx.x;
  const int b0 = blockIdx.y << 4;      // 16 batches per block
  const int tid = threadIdx.x;
  const int lane = tid & 63;
  const int w = tid >> 6;              // wave 0..7
  const int hh = (w << 4) + (lane & 15);  // this lane's h row (B-frag row & gate col)
  const int lg = lane >> 4;            // k-group 0..3

  // ---- weight fragments in registers: frag(gate,ks): lane holds
  // W[f][gate*128+hh][ks*32 + lg*8 + j], split into bf16 hi+lo.
  s8v wh[12], wl[12];
#pragma unroll
  for (int gate = 0; gate < 3; gate++) {
#pragma unroll
    for (int ks = 0; ks < 4; ks++) {
      const float* wp = Whh + ((size_t)f * H3c + gate * Hc + hh) * Hc + (ks << 5) + (lg << 3);
      s8v hi, lo;
#pragma unroll
      for (int j = 0; j < 8; j++) {
        float v = wp[j];
        unsigned short hb = f2b(v);
        unsigned short lb = f2b(v - b2f(hb));
        hi[j] = (short)hb;
        lo[j] = (short)lb;
      }
      wh[gate * 4 + ks] = hi;
      wl[gate * 4 + ks] = lo;
    }
  }

  // gate coefficients for this lane's h (shared by its 4 batches)
  const float wi0 = Wih[f * H3c + hh], wi1 = Wih[f * H3c + Hc + hh], wi2 = Wih[f * H3c + 2 * Hc + hh];
  const float bi0 = bih[f * H3c + hh], bi1 = bih[f * H3c + Hc + hh], bi2 = bih[f * H3c + 2 * Hc + hh];
  const float bh0 = bhh[f * H3c + hh], bh1 = bhh[f * H3c + Hc + hh], bh2 = bhh[f * H3c + 2 * Hc + hh];

  __shared__ unsigned short hbuf[2][2][16 * 128];  // [buf][hi/lo][swizzled idx]
  __shared__ float xs[16][100];                    // x staged, padded stride

  {
    unsigned short* hz = &hbuf[0][0][0];
    for (int i = tid; i < 2 * 2 * 16 * 128; i += 512) hz[i] = 0;
    for (int i = tid; i < 16 * Tc; i += 512) {
      int b = i / Tc, t = i - b * Tc;
      xs[b][t] = x[((size_t)(b0 + b) * Tc + t) * Fc + f];
    }
  }
  __syncthreads();

  float hold[4] = {0.f, 0.f, 0.f, 0.f};  // fp32 master h for batches lg*4+r
  int cur = 0;

  for (int t = 0; t < Tc; t++) {
    // ---- A-fragments from LDS (h of previous step), swizzled b128 reads ----
    s8v ahi[4], alo[4];
#pragma unroll
    for (int ks = 0; ks < 4; ks++) {
      int m = lane & 15;                                   // batch row
      int idx = m * 128 + ((((ks << 2) + lg) ^ (m & 7)) << 3);
      ahi[ks] = *reinterpret_cast<const s8v*>(&hbuf[cur][0][idx]);
      alo[ks] = *reinterpret_cast<const s8v*>(&hbuf[cur][1][idx]);
    }
    // ---- 3 gates x 4 k-steps x 3 split-products ----
    f4v accr = {0.f, 0.f, 0.f, 0.f}, accz = {0.f, 0.f, 0.f, 0.f}, accn = {0.f, 0.f, 0.f, 0.f};
#pragma unroll
    for (int ks = 0; ks < 4; ks++) {
      accr = __builtin_amdgcn_mfma_f32_16x16x32_bf16(ahi[ks], wh[0 + ks], accr, 0, 0, 0);
      accz = __builtin_amdgcn_mfma_f32_16x16x32_bf16(ahi[ks], wh[4 + ks], accz, 0, 0, 0);
      accn = __builtin_amdgcn_mfma_f32_16x16x32_bf16(ahi[ks], wh[8 + ks], accn, 0, 0, 0);
      accr = __builtin_amdgcn_mfma_f32_16x16x32_bf16(alo[ks], wh[0 + ks], accr, 0, 0, 0);
      accz = __builtin_amdgcn_mfma_f32_16x16x32_bf16(alo[ks], wh[4 + ks], accz, 0, 0, 0);
      accn = __builtin_amdgcn_mfma_f32_16x16x32_bf16(alo[ks], wh[8 + ks], accn, 0, 0, 0);
      accr = __builtin_amdgcn_mfma_f32_16x16x32_bf16(ahi[ks], wl[0 + ks], accr, 0, 0, 0);
      accz = __builtin_amdgcn_mfma_f32_16x16x32_bf16(ahi[ks], wl[4 + ks], accz, 0, 0, 0);
      accn = __builtin_amdgcn_mfma_f32_16x16x32_bf16(ahi[ks], wl[8 + ks], accn, 0, 0, 0);
    }
    // ---- gates + h update, in-register (lane has r,z,n for its (b,h)) ----
    int nxt = cur ^ 1;
#pragma unroll
    for (int r = 0; r < 4; r++) {
      int bt = (lg << 2) + r;  // batch within chunk (D row = (lane>>4)*4+reg)
      float xv = xs[bt][t];
      float rr = sigf_fast(xv * wi0 + bi0 + accr[r] + bh0);
      float zz = sigf_fast(xv * wi1 + bi1 + accz[r] + bh1);
      float nn = tanhf_fast(xv * wi2 + bi2 + rr * (accn[r] + bh2));
      float hn = (1.f - zz) * nn + zz * hold[r];
      hold[r] = hn;
      stv(&Hs[(((size_t)(b0 + bt) * Tc + t) * Fc + f) * Hc + hh], hn);
      unsigned short hb = f2b(hn);
      unsigned short lb = f2b(hn - b2f(hb));
      int widx = bt * 128 + (((hh >> 3) ^ (bt & 7)) << 3) + (hh & 7);
      hbuf[nxt][0][widx] = hb;
      hbuf[nxt][1][widx] = lb;
    }
    cur = nxt;
    __syncthreads();
  }
#pragma unroll
  for (int r = 0; r < 4; r++) {
    int bt = (lg << 2) + r;
    hT[((size_t)(b0 + bt) * Fc + f) * Hc + hh] = hold[r];
  }
}

// ---------------------------------------------------------------------------
// Kernel B: time-aware per-feature attention. Block per (f,b), 256 threads.
// ---------------------------------------------------------------------------
template <typename ST>
__global__ __launch_bounds__(256) void feat_attn(
    const ST* __restrict__ Hs, const float* __restrict__ hT,
    const float* __restrict__ Wt, const float* __restrict__ Wx,
    const float* __restrict__ rate, float* __restrict__ posi) {
  const int f = blockIdx.x, b = blockIdx.y;
  const int tid = threadIdx.x;
  __shared__ float tile[Tc][Hc + 1];
  __shared__ float wxs[Hc][Ac];
  __shared__ float qs[Ac];
  __shared__ float es[Tc];
  __shared__ float red[2];

  for (int i = tid; i < Tc * (Hc / 4); i += 256) {
    int t = i >> 5, k = (i & 31) << 2;
    float o[4];
    ld4(&Hs[(((size_t)b * Tc + t) * Fc + f) * Hc + k], o);
    tile[t][k] = o[0]; tile[t][k + 1] = o[1]; tile[t][k + 2] = o[2]; tile[t][k + 3] = o[3];
  }
  for (int i = tid; i < Hc * Ac; i += 256) (&wxs[0][0])[i] = Wx[(size_t)f * Hc * Ac + i];
  if (tid < Ac) {
    float q = 0.f;
    const float* hTp = hT + ((size_t)b * Fc + f) * Hc;
    for (int h = 0; h < Hc; h++) q += hTp[h] * Wt[((size_t)f * Hc + h) * Ac + tid];
    qs[tid] = q;
  }
  __syncthreads();
  if (tid < Tc) {
    float ka[Ac];
#pragma unroll
    for (int a = 0; a < Ac; a++) ka[a] = 0.f;
    for (int h = 0; h < Hc; h++) {
      float hv = tile[tid][h];
#pragma unroll
      for (int a = 0; a < Ac; a++) ka[a] += hv * wxs[h][a];
    }
    float dot = 0.f;
#pragma unroll
    for (int a = 0; a < Ac; a++) dot += qs[a] * ka[a];
    float sd = sigf(dot);
    float denom = sigf(rate[f]) * (logf(2.72f + (1.f - sd)) * (float)(Tc - tid));
    es[tid] = fmaxf(sd / denom, 0.f);
  }
  __syncthreads();
  if (tid == 0) {
    float m = -1e30f;
    for (int t = 0; t < Tc; t++) m = fmaxf(m, es[t]);
    red[0] = m;
  }
  __syncthreads();
  if (tid < Tc) es[tid] = expf(es[tid] - red[0]);
  __syncthreads();
  if (tid == 0) {
    float s = 0.f;
    for (int t = 0; t < Tc; t++) s += es[t];
    red[1] = 1.f / s;
  }
  __syncthreads();
  if (tid < Hc) {
    float acc = 0.f;
    for (int t = 0; t < Tc; t++) acc += es[t] * tile[t][tid];
    posi[((size_t)b * Nc + f) * Hc + tid] = acc * red[1];
  }
}

// ---------------------------------------------------------------------------
__global__ __launch_bounds__(128) void demo_k(
    const float* __restrict__ demo, const float* __restrict__ dW,
    const float* __restrict__ db, float* __restrict__ posi) {
  int b = blockIdx.x, h = threadIdx.x;
  float acc = db[h];
  const float* dp = demo + b * DEMOc;
  const float* wp = dW + h * DEMOc;
#pragma unroll
  for (int d = 0; d < DEMOc; d++) acc += dp[d] * wp[d];
  posi[((size_t)b * Nc + (Nc - 1)) * Hc + h] = tanhf(acc);
}

__global__ __launch_bounds__(128) void ln_qkv(
    const float* __restrict__ posi, const float* __restrict__ ga, const float* __restrict__ be,
    const float* __restrict__ Wq, const float* __restrict__ bq,
    const float* __restrict__ Wk, const float* __restrict__ bk,
    const float* __restrict__ Wv, const float* __restrict__ bv,
    float* __restrict__ qb, float* __restrict__ kb, float* __restrict__ vb) {
  int bn = blockIdx.x;
  int b = bn / Nc, n = bn % Nc;
  int h = threadIdx.x;
  __shared__ float xn[Hc];
  __shared__ float red[2];
  float xv = posi[(size_t)bn * Hc + h];
  float m = bsum(xv, red, 2) * (1.f / Hc);
  float d = xv - m;
  float var = bsum(d * d, red, 2) * (1.f / (Hc - 1));
  xn[h] = ga[h] * d / (sqrtf(var) + 1e-7f) + be[h];
  __syncthreads();
  float q = bq[h], k = bk[h], v = bv[h];
  for (int kk = 0; kk < Hc; kk++) {
    float xk = xn[kk];
    q += xk * Wq[h * Hc + kk];
    k += xk * Wk[h * Hc + kk];
    v += xk * Wv[h * Hc + kk];
  }
  int head = h >> 5, dd = h & 31;
  size_t o = (((size_t)b * NHc + head) * Nc + n) * DKc + dd;
  qb[o] = q; kb[o] = k; vb[o] = v;
}

__global__ __launch_bounds__(64) void mha_attn(
    const float* __restrict__ qb, const float* __restrict__ kb,
    const float* __restrict__ vb, float* __restrict__ ctx) {
  int hd = blockIdx.x, b = blockIdx.y;
  int tid = threadIdx.x;
  __shared__ float ksm[Nc][DKc];
  __shared__ float vsm[Nc][DKc];
  __shared__ float sc[Nc][Nc];
  size_t base = ((size_t)b * NHc + hd) * Nc * DKc;
  for (int i = tid; i < Nc * DKc; i += 64) {
    ksm[i / DKc][i % DKc] = kb[base + i];
    vsm[i / DKc][i % DKc] = vb[base + i];
  }
  __syncthreads();
  if (tid < Nc) {
    float qr[DKc];
#pragma unroll
    for (int d = 0; d < DKc; d++) qr[d] = qb[base + tid * DKc + d];
    float mx = -1e30f;
    for (int mm = 0; mm < Nc; mm++) {
      float s = 0.f;
#pragma unroll
      for (int d = 0; d < DKc; d++) s += qr[d] * ksm[mm][d];
      s *= 0.17677669529663687f;  // 1/sqrt(32)
      sc[tid][mm] = s;
      mx = fmaxf(mx, s);
    }
    float ssum = 0.f;
    for (int mm = 0; mm < Nc; mm++) {
      float e = expf(sc[tid][mm] - mx);
      sc[tid][mm] = e;
      ssum += e;
    }
    float inv = 1.f / ssum;
    float acc[DKc];
#pragma unroll
    for (int d = 0; d < DKc; d++) acc[d] = 0.f;
    for (int mm = 0; mm < Nc; mm++) {
      float p = sc[tid][mm] * inv;
#pragma unroll
      for (int d = 0; d < DKc; d++) acc[d] += p * vsm[mm][d];
    }
    float* cp = ctx + ((size_t)b * Nc + tid) * Hc + hd * DKc;
#pragma unroll
    for (int d = 0; d < DKc; d++) cp[d] = acc[d];
  }
}

__global__ __launch_bounds__(128) void wo_res(
    const float* __restrict__ ctx, const float* __restrict__ Wo,
    const float* __restrict__ bo, const float* __restrict__ posi,
    float* __restrict__ mha, float* __restrict__ h1) {
  int bn = blockIdx.x;
  int h = threadIdx.x;
  __shared__ float cs[Hc];
  cs[h] = ctx[(size_t)bn * Hc + h];
  __syncthreads();
  float acc = bo[h];
  for (int k = 0; k < Hc; k++) acc += cs[k] * Wo[h * Hc + k];
  mha[(size_t)bn * Hc + h] = acc;
  h1[(size_t)bn * Hc + h] = posi[(size_t)bn * Hc + h] + acc;
}

__global__ __launch_bounds__(256) void decov_k(
    const float* __restrict__ mha, float* __restrict__ dacc) {
  int n = blockIdx.x;
  int tid = threadIdx.x;
  __shared__ float xc[Bc][Hc];
  __shared__ float red[4];
  for (int i = tid; i < Bc * Hc; i += 256) {
    int b = i >> 7, h = i & 127;
    xc[b][h] = mha[((size_t)b * Nc + n) * Hc + h];
  }
  __syncthreads();
  if (tid < Hc) {
    float s = 0.f;
    for (int b = 0; b < Bc; b++) s += xc[b][tid];
    s *= (1.f / Bc);
    for (int b = 0; b < Bc; b++) xc[b][tid] -= s;
  }
  __syncthreads();
  float p2 = 0.f, pd = 0.f;
  for (int e = tid; e < Hc * Hc; e += 256) {
    int hh = e >> 7, gg = e & 127;
    float c = 0.f;
    for (int b = 0; b < Bc; b++) c += xc[b][hh] * xc[b][gg];
    c *= (1.f / (Bc - 1));
    float c2 = c * c;
    p2 += c2;
    if (hh == gg) pd += c2;
  }
  float s2 = bsum(p2, red, 4);
  float sdg = bsum(pd, red, 4);
  if (tid == 0) atomicAdd(dacc, 0.5f * (s2 - sdg));
}

__global__ __launch_bounds__(256) void ln2_ffn1(
    const float* __restrict__ h1, const float* __restrict__ ga, const float* __restrict__ be,
    const float* __restrict__ W1, const float* __restrict__ b1, float* __restrict__ t1) {
  int bn = blockIdx.x;
  int tid = threadIdx.x;
  __shared__ float xn[Hc];
  __shared__ float red[4];
  float xv = (tid < Hc) ? h1[(size_t)bn * Hc + tid] : 0.f;
  float m = bsum(xv, red, 4) * (1.f / Hc);
  float d = (tid < Hc) ? (xv - m) : 0.f;
  float var = bsum(d * d, red, 4) * (1.f / (Hc - 1));
  if (tid < Hc) xn[tid] = ga[tid] * d / (sqrtf(var) + 1e-7f) + be[tid];
  __syncthreads();
#pragma unroll
  for (int jj = 0; jj < 2; jj++) {
    int j = tid + jj * 256;
    float acc = b1[j];
    for (int k = 0; k < Hc; k++) acc += xn[k] * W1[j * Hc + k];
    t1[(size_t)bn * DFFc + j] = fmaxf(acc, 0.f);
  }
}

__global__ __launch_bounds__(128) void ffn2_res(
    const float* __restrict__ t1, const float* __restrict__ W2,
    const float* __restrict__ b2, const float* __restrict__ h1, float* __restrict__ h2) {
  int bn = blockIdx.x;
  int h = threadIdx.x;
  __shared__ float ts[DFFc];
  for (int i = h; i < DFFc; i += 128) ts[i] = t1[(size_t)bn * DFFc + i];
  __syncthreads();
  float acc = b2[h];
  for (int j = 0; j < DFFc; j++) acc += ts[j] * W2[h * DFFc + j];
  h2[(size_t)bn * Hc + h] = h1[(size_t)bn * Hc + h] + acc;
}

__global__ __launch_bounds__(128) void final_k(
    const float* __restrict__ h2,
    const float* __restrict__ Wq, const float* __restrict__ bq,
    const float* __restrict__ Wk, const float* __restrict__ bk,
    const float* __restrict__ Wv, const float* __restrict__ bv,
    const float* __restrict__ oW, const float* __restrict__ ob,
    const float* __restrict__ dacc, float* __restrict__ out) {
  int b = blockIdx.x, h = threadIdx.x;
  __shared__ float h2s[Nc][Hc];
  __shared__ float fks[Nc][Hc + 1];
  __shared__ float fqs[Hc];
  __shared__ float alphas[Nc];
  __shared__ float red[2];
  __shared__ float r2[2];
  for (int i = h; i < Nc * Hc; i += 128) h2s[i / Hc][i % Hc] = h2[(size_t)b * Nc * Hc + i];
  __syncthreads();
  {
    float q = bq[h];
    for (int k = 0; k < Hc; k++) q += h2s[Nc - 1][k] * Wq[h * Hc + k];
    fqs[h] = q;
  }
  for (int n = 0; n < Nc; n++) {
    float fk = bk[h];
    for (int k = 0; k < Hc; k++) fk += h2s[n][k] * Wk[h * Hc + k];
    fks[n][h] = fk;
  }
  __syncthreads();
  if (h < Nc) {
    float fe = 0.f;
    for (int k = 0; k < Hc; k++) fe += fks[h][k] * fqs[k];
    alphas[h] = fe;
  }
  __syncthreads();
  if (h == 0) {
    float m = -1e30f;
    for (int n = 0; n < Nc; n++) m = fmaxf(m, alphas[n]);
    float s = 0.f;
    for (int n = 0; n < Nc; n++) {
      float e = expf(alphas[n] - m);
      alphas[n] = e;
      s += e;
    }
    red[0] = 1.f / s;
  }
  __syncthreads();
  float inv = red[0];
  float pv = 0.f;
  for (int n = 0; n < Nc; n++) {
    float fv = bv[h];
    for (int k = 0; k < Hc; k++) fv += h2s[n][k] * Wv[h * Hc + k];
    pv += alphas[n] * fv;
  }
  pv *= inv;
  float c = pv * oW[h];
#pragma unroll
  for (int off = 32; off > 0; off >>= 1) c += __shfl_down(c, off);
  int lane = h & 63, wid = h >> 6;
  if (lane == 0) r2[wid] = c;
  __syncthreads();
  if (h == 0) {
    out[b] = sigf(r2[0] + r2[1] + ob[0]);
    if (b == 0) out[Bc] = dacc[0];
  }
}

}  // namespace

extern "C" void kernel_launch(void* const* d_in, const int* in_sizes, int n_in,
                              void* d_out, int out_size, void* d_ws, size_t ws_size,
                              hipStream_t stream) {
  const float* x    = (const float*)d_in[0];
  const float* demo = (const float*)d_in[1];
  const float* gWih = (const float*)d_in[2];
  const float* gWhh = (const float*)d_in[3];
  const float* gbih = (const float*)d_in[4];
  const float* gbhh = (const float*)d_in[5];
  const float* aWt  = (const float*)d_in[6];
  const float* aWx  = (const float*)d_in[7];
  const float* aRt  = (const float*)d_in[8];
  const float* dW   = (const float*)d_in[9];
  const float* db   = (const float*)d_in[10];
  const float* mWq  = (const float*)d_in[11];
  const float* mbq  = (const float*)d_in[12];
  const float* mWk  = (const float*)d_in[13];
  const float* mbk  = (const float*)d_in[14];
  const float* mWv  = (const float*)d_in[15];
  const float* mbv  = (const float*)d_in[16];
  const float* mWo  = (const float*)d_in[17];
  const float* mbo  = (const float*)d_in[18];
  const float* l1a  = (const float*)d_in[19];
  const float* l1b  = (const float*)d_in[20];
  const float* l2a  = (const float*)d_in[21];
  const float* l2b  = (const float*)d_in[22];
  const float* fW1  = (const float*)d_in[23];
  const float* fb1  = (const float*)d_in[24];
  const float* fW2  = (const float*)d_in[25];
  const float* fb2  = (const float*)d_in[26];
  const float* fWq  = (const float*)d_in[27];
  const float* fbq  = (const float*)d_in[28];
  const float* fWk  = (const float*)d_in[29];
  const float* fbk  = (const float*)d_in[30];
  const float* fWv  = (const float*)d_in[31];
  const float* fbv  = (const float*)d_in[32];
  const float* oW   = (const float*)d_in[33];
  const float* ob   = (const float*)d_in[34];

  char* base = (char*)d_ws;
  size_t off = 0;
  auto take = [&](size_t nfloats) -> float* {
    float* r = (float*)(base + off);
    off += ((nfloats * sizeof(float)) + 255) & ~(size_t)255;
    return r;
  };
  float* dec  = take(64);
  float* hT   = take((size_t)Bc * Fc * Hc);
  float* posi = take((size_t)Bc * Nc * Hc);
  float* qb   = take((size_t)Bc * Nc * Hc);
  float* kb   = take((size_t)Bc * Nc * Hc);
  float* vb   = take((size_t)Bc * Nc * Hc);
  float* ctx  = take((size_t)Bc * Nc * Hc);
  float* mha  = take((size_t)Bc * Nc * Hc);
  float* h1   = take((size_t)Bc * Nc * Hc);
  float* t1   = take((size_t)Bc * Nc * DFFc);
  float* h2   = take((size_t)Bc * Nc * Hc);
  size_t HsElems = (size_t)Bc * Tc * Fc * Hc;  // 37.7M
  void* HsPtr = (void*)(base + off);
  bool f32path = (ws_size >= off + HsElems * sizeof(float));

  hipMemsetAsync(dec, 0, sizeof(float), stream);

  dim3 gGru(Fc, Bc / 16);
  dim3 gAtt(Fc, Bc);
  if (f32path) {
    gru_mfma<float><<<gGru, 512, 0, stream>>>(x, gWih, gWhh, gbih, gbhh, (float*)HsPtr, hT);
    feat_attn<float><<<gAtt, 256, 0, stream>>>((const float*)HsPtr, hT, aWt, aWx, aRt, posi);
  } else {
    gru_mfma<__hip_bfloat16><<<gGru, 512, 0, stream>>>(x, gWih, gWhh, gbih, gbhh,
                                                       (__hip_bfloat16*)HsPtr, hT);
    feat_attn<__hip_bfloat16><<<gAtt, 256, 0, stream>>>((const __hip_bfloat16*)HsPtr, hT,
                                                        aWt, aWx, aRt, posi);
  }
  demo_k<<<Bc, 128, 0, stream>>>(demo, dW, db, posi);
  ln_qkv<<<Bc * Nc, 128, 0, stream>>>(posi, l1a, l1b, mWq, mbq, mWk, mbk, mWv, mbv, qb, kb, vb);
  mha_attn<<<dim3(NHc, Bc), 64, 0, stream>>>(qb, kb, vb, ctx);
  wo_res<<<Bc * Nc, 128, 0, stream>>>(ctx, mWo, mbo, posi, mha, h1);
  decov_k<<<Nc, 256, 0, stream>>>(mha, dec);
  ln2_ffn1<<<Bc * Nc, 256, 0, stream>>>(h1, l2a, l2b, fW1, fb1, t1);
  ffn2_res<<<Bc * Nc, 128, 0, stream>>>(t1, fW2, fb2, h1, h2);
  final_k<<<Bc, 128, 0, stream>>>(h2, fWq, fbq, fWk, fbk, fWv, fbv, oW, ob, dec, (float*)d_out);
}

// Round 8
// 773.182 us; speedup vs baseline: 7.0808x; 1.1565x over previous
//
#include <hip/hip_runtime.h>
#include <hip/hip_bf16.h>

namespace {

constexpr int Bc = 64, Tc = 96, Fc = 48, Hc = 128, Ac = 8;
constexpr int DFFc = 512, DEMOc = 12, NHc = 4, Nc = 49, H3c = 384, DKc = 32;

typedef __attribute__((ext_vector_type(8))) short s8v;   // 8 bf16 = 4 VGPR (MFMA A/B frag)
typedef __attribute__((ext_vector_type(4))) float f4v;   // MFMA C/D frag

__device__ __forceinline__ float sigf(float x) { return 1.f / (1.f + expf(-x)); }
__device__ __forceinline__ float sigf_fast(float x) { return 1.f / (1.f + __expf(-x)); }
__device__ __forceinline__ float tanhf_fast(float x) {
  float e = __expf(2.f * x);
  return 1.f - 2.f / (e + 1.f);   // +-inf safe: ->1 / ->-1
}

__device__ __forceinline__ unsigned short f2b(float v) {   // fp32 -> bf16 bits (RNE)
  __hip_bfloat16 h = __float2bfloat16(v);
  union { __hip_bfloat16 b; unsigned short u; } c;
  c.b = h;
  return c.u;
}
__device__ __forceinline__ float b2f(unsigned short u) {
  union { unsigned u32; float f; } c;
  c.u32 = (unsigned)u << 16;
  return c.f;
}

template <typename ST> __device__ __forceinline__ void stv(ST* p, float v);
template <> __device__ __forceinline__ void stv<float>(float* p, float v) { *p = v; }
template <> __device__ __forceinline__ void stv<__hip_bfloat16>(__hip_bfloat16* p, float v) {
  *p = __float2bfloat16(v);
}

template <typename ST> __device__ __forceinline__ void ld4(const ST* p, float* o);
template <> __device__ __forceinline__ void ld4<float>(const float* p, float* o) {
  float4 v = *reinterpret_cast<const float4*>(p);
  o[0] = v.x; o[1] = v.y; o[2] = v.z; o[3] = v.w;
}
template <> __device__ __forceinline__ void ld4<__hip_bfloat16>(const __hip_bfloat16* p, float* o) {
  ushort4 v = *reinterpret_cast<const ushort4*>(p);
  union { unsigned u; float f; } t;
  t.u = (unsigned)v.x << 16; o[0] = t.f;
  t.u = (unsigned)v.y << 16; o[1] = t.f;
  t.u = (unsigned)v.z << 16; o[2] = t.f;
  t.u = (unsigned)v.w << 16; o[3] = t.f;
}

// block reduce over nw waves (blockDim = nw*64); all threads must call
__device__ __forceinline__ float bsum(float v, float* red, int nw) {
#pragma unroll
  for (int off = 32; off > 0; off >>= 1) v += __shfl_down(v, off);
  int lane = threadIdx.x & 63, wid = threadIdx.x >> 6;
  __syncthreads();
  if (lane == 0) red[wid] = v;
  __syncthreads();
  float s = 0.f;
  for (int i = 0; i < nw; i++) s += red[i];
  return s;
}

// ---------------------------------------------------------------------------
// GRU scan via MFMA (r5; measured r6: total 1863->894us, gru no longer top).
// History: r2 fp32-weights spill -> 11.3 GB scratch, 4820us. r4: allocator
// refused promotion (VGPR=96), L2-latency-bound, 1130us. r5: MFMA + split-bf16.
// ---------------------------------------------------------------------------
template <typename ST>
__global__ __launch_bounds__(512, 2) void gru_mfma(
    const float* __restrict__ x, const float* __restrict__ Wih,
    const float* __restrict__ Whh, const float* __restrict__ bih,
    const float* __restrict__ bhh, ST* __restrict__ Hs, float* __restrict__ hT) {
  const int f = blockIdx.x;
  const int b0 = blockIdx.y << 4;      // 16 batches per block
  const int tid = threadIdx.x;
  const int lane = tid & 63;
  const int w = tid >> 6;              // wave 0..7
  const int hh = (w << 4) + (lane & 15);  // this lane's h row (B-frag row & gate col)
  const int lg = lane >> 4;            // k-group 0..3

  s8v wh[12], wl[12];
#pragma unroll
  for (int gate = 0; gate < 3; gate++) {
#pragma unroll
    for (int ks = 0; ks < 4; ks++) {
      const float* wp = Whh + ((size_t)f * H3c + gate * Hc + hh) * Hc + (ks << 5) + (lg << 3);
      s8v hi, lo;
#pragma unroll
      for (int j = 0; j < 8; j++) {
        float v = wp[j];
        unsigned short hb = f2b(v);
        unsigned short lb = f2b(v - b2f(hb));
        hi[j] = (short)hb;
        lo[j] = (short)lb;
      }
      wh[gate * 4 + ks] = hi;
      wl[gate * 4 + ks] = lo;
    }
  }

  const float wi0 = Wih[f * H3c + hh], wi1 = Wih[f * H3c + Hc + hh], wi2 = Wih[f * H3c + 2 * Hc + hh];
  const float bi0 = bih[f * H3c + hh], bi1 = bih[f * H3c + Hc + hh], bi2 = bih[f * H3c + 2 * Hc + hh];
  const float bh0 = bhh[f * H3c + hh], bh1 = bhh[f * H3c + Hc + hh], bh2 = bhh[f * H3c + 2 * Hc + hh];

  __shared__ unsigned short hbuf[2][2][16 * 128];  // [buf][hi/lo][swizzled idx]
  __shared__ float xs[16][100];                    // x staged, padded stride

  {
    unsigned short* hz = &hbuf[0][0][0];
    for (int i = tid; i < 2 * 2 * 16 * 128; i += 512) hz[i] = 0;
    for (int i = tid; i < 16 * Tc; i += 512) {
      int b = i / Tc, t = i - b * Tc;
      xs[b][t] = x[((size_t)(b0 + b) * Tc + t) * Fc + f];
    }
  }
  __syncthreads();

  float hold[4] = {0.f, 0.f, 0.f, 0.f};  // fp32 master h for batches lg*4+r
  int cur = 0;

  for (int t = 0; t < Tc; t++) {
    s8v ahi[4], alo[4];
#pragma unroll
    for (int ks = 0; ks < 4; ks++) {
      int m = lane & 15;                                   // batch row
      int idx = m * 128 + ((((ks << 2) + lg) ^ (m & 7)) << 3);
      ahi[ks] = *reinterpret_cast<const s8v*>(&hbuf[cur][0][idx]);
      alo[ks] = *reinterpret_cast<const s8v*>(&hbuf[cur][1][idx]);
    }
    f4v accr = {0.f, 0.f, 0.f, 0.f}, accz = {0.f, 0.f, 0.f, 0.f}, accn = {0.f, 0.f, 0.f, 0.f};
#pragma unroll
    for (int ks = 0; ks < 4; ks++) {
      accr = __builtin_amdgcn_mfma_f32_16x16x32_bf16(ahi[ks], wh[0 + ks], accr, 0, 0, 0);
      accz = __builtin_amdgcn_mfma_f32_16x16x32_bf16(ahi[ks], wh[4 + ks], accz, 0, 0, 0);
      accn = __builtin_amdgcn_mfma_f32_16x16x32_bf16(ahi[ks], wh[8 + ks], accn, 0, 0, 0);
      accr = __builtin_amdgcn_mfma_f32_16x16x32_bf16(alo[ks], wh[0 + ks], accr, 0, 0, 0);
      accz = __builtin_amdgcn_mfma_f32_16x16x32_bf16(alo[ks], wh[4 + ks], accz, 0, 0, 0);
      accn = __builtin_amdgcn_mfma_f32_16x16x32_bf16(alo[ks], wh[8 + ks], accn, 0, 0, 0);
      accr = __builtin_amdgcn_mfma_f32_16x16x32_bf16(ahi[ks], wl[0 + ks], accr, 0, 0, 0);
      accz = __builtin_amdgcn_mfma_f32_16x16x32_bf16(ahi[ks], wl[4 + ks], accz, 0, 0, 0);
      accn = __builtin_amdgcn_mfma_f32_16x16x32_bf16(ahi[ks], wl[8 + ks], accn, 0, 0, 0);
    }
    int nxt = cur ^ 1;
#pragma unroll
    for (int r = 0; r < 4; r++) {
      int bt = (lg << 2) + r;  // batch within chunk (D row = (lane>>4)*4+reg)
      float xv = xs[bt][t];
      float rr = sigf_fast(xv * wi0 + bi0 + accr[r] + bh0);
      float zz = sigf_fast(xv * wi1 + bi1 + accz[r] + bh1);
      float nn = tanhf_fast(xv * wi2 + bi2 + rr * (accn[r] + bh2));
      float hn = (1.f - zz) * nn + zz * hold[r];
      hold[r] = hn;
      stv(&Hs[(((size_t)(b0 + bt) * Tc + t) * Fc + f) * Hc + hh], hn);
      unsigned short hb = f2b(hn);
      unsigned short lb = f2b(hn - b2f(hb));
      int widx = bt * 128 + (((hh >> 3) ^ (bt & 7)) << 3) + (hh & 7);
      hbuf[nxt][0][widx] = hb;
      hbuf[nxt][1][widx] = lb;
    }
    cur = nxt;
    __syncthreads();
  }
#pragma unroll
  for (int r = 0; r < 4; r++) {
    int bt = (lg << 2) + r;
    hT[((size_t)(b0 + bt) * Fc + f) * Hc + hh] = hold[r];
  }
}

// ---------------------------------------------------------------------------
// Kernel B: time-aware per-feature attention. Block per (f,b), 256 threads.
// ---------------------------------------------------------------------------
template <typename ST>
__global__ __launch_bounds__(256) void feat_attn(
    const ST* __restrict__ Hs, const float* __restrict__ hT,
    const float* __restrict__ Wt, const float* __restrict__ Wx,
    const float* __restrict__ rate, float* __restrict__ posi) {
  const int f = blockIdx.x, b = blockIdx.y;
  const int tid = threadIdx.x;
  __shared__ float tile[Tc][Hc + 1];
  __shared__ float wxs[Hc][Ac];
  __shared__ float qs[Ac];
  __shared__ float es[Tc];
  __shared__ float red[2];

  for (int i = tid; i < Tc * (Hc / 4); i += 256) {
    int t = i >> 5, k = (i & 31) << 2;
    float o[4];
    ld4(&Hs[(((size_t)b * Tc + t) * Fc + f) * Hc + k], o);
    tile[t][k] = o[0]; tile[t][k + 1] = o[1]; tile[t][k + 2] = o[2]; tile[t][k + 3] = o[3];
  }
  for (int i = tid; i < Hc * Ac; i += 256) (&wxs[0][0])[i] = Wx[(size_t)f * Hc * Ac + i];
  if (tid < Ac) {
    float q = 0.f;
    const float* hTp = hT + ((size_t)b * Fc + f) * Hc;
    for (int h = 0; h < Hc; h++) q += hTp[h] * Wt[((size_t)f * Hc + h) * Ac + tid];
    qs[tid] = q;
  }
  __syncthreads();
  if (tid < Tc) {
    float ka[Ac];
#pragma unroll
    for (int a = 0; a < Ac; a++) ka[a] = 0.f;
    for (int h = 0; h < Hc; h++) {
      float hv = tile[tid][h];
#pragma unroll
      for (int a = 0; a < Ac; a++) ka[a] += hv * wxs[h][a];
    }
    float dot = 0.f;
#pragma unroll
    for (int a = 0; a < Ac; a++) dot += qs[a] * ka[a];
    float sd = sigf(dot);
    float denom = sigf(rate[f]) * (logf(2.72f + (1.f - sd)) * (float)(Tc - tid));
    es[tid] = fmaxf(sd / denom, 0.f);
  }
  __syncthreads();
  if (tid == 0) {
    float m = -1e30f;
    for (int t = 0; t < Tc; t++) m = fmaxf(m, es[t]);
    red[0] = m;
  }
  __syncthreads();
  if (tid < Tc) es[tid] = expf(es[tid] - red[0]);
  __syncthreads();
  if (tid == 0) {
    float s = 0.f;
    for (int t = 0; t < Tc; t++) s += es[t];
    red[1] = 1.f / s;
  }
  __syncthreads();
  if (tid < Hc) {
    float acc = 0.f;
    for (int t = 0; t < Tc; t++) acc += es[t] * tile[t][tid];
    posi[((size_t)b * Nc + f) * Hc + tid] = acc * red[1];
  }
}

// ---------------------------------------------------------------------------
__global__ __launch_bounds__(128) void demo_k(
    const float* __restrict__ demo, const float* __restrict__ dW,
    const float* __restrict__ db, float* __restrict__ posi) {
  int b = blockIdx.x, h = threadIdx.x;
  float acc = db[h];
  const float* dp = demo + b * DEMOc;
  const float* wp = dW + h * DEMOc;
#pragma unroll
  for (int d = 0; d < DEMOc; d++) acc += dp[d] * wp[d];
  posi[((size_t)b * Nc + (Nc - 1)) * Hc + h] = tanhf(acc);
}

__global__ __launch_bounds__(128) void ln_qkv(
    const float* __restrict__ posi, const float* __restrict__ ga, const float* __restrict__ be,
    const float* __restrict__ Wq, const float* __restrict__ bq,
    const float* __restrict__ Wk, const float* __restrict__ bk,
    const float* __restrict__ Wv, const float* __restrict__ bv,
    float* __restrict__ qb, float* __restrict__ kb, float* __restrict__ vb) {
  int bn = blockIdx.x;
  int b = bn / Nc, n = bn % Nc;
  int h = threadIdx.x;
  __shared__ float xn[Hc];
  __shared__ float red[2];
  float xv = posi[(size_t)bn * Hc + h];
  float m = bsum(xv, red, 2) * (1.f / Hc);
  float d = xv - m;
  float var = bsum(d * d, red, 2) * (1.f / (Hc - 1));
  xn[h] = ga[h] * d / (sqrtf(var) + 1e-7f) + be[h];
  __syncthreads();
  float q = bq[h], k = bk[h], v = bv[h];
  for (int kk = 0; kk < Hc; kk++) {
    float xk = xn[kk];
    q += xk * Wq[h * Hc + kk];
    k += xk * Wk[h * Hc + kk];
    v += xk * Wv[h * Hc + kk];
  }
  int head = h >> 5, dd = h & 31;
  size_t o = (((size_t)b * NHc + head) * Nc + n) * DKc + dd;
  qb[o] = q; kb[o] = k; vb[o] = v;
}

__global__ __launch_bounds__(64) void mha_attn(
    const float* __restrict__ qb, const float* __restrict__ kb,
    const float* __restrict__ vb, float* __restrict__ ctx) {
  int hd = blockIdx.x, b = blockIdx.y;
  int tid = threadIdx.x;
  __shared__ float ksm[Nc][DKc];
  __shared__ float vsm[Nc][DKc];
  __shared__ float sc[Nc][Nc];
  size_t base = ((size_t)b * NHc + hd) * Nc * DKc;
  for (int i = tid; i < Nc * DKc; i += 64) {
    ksm[i / DKc][i % DKc] = kb[base + i];
    vsm[i / DKc][i % DKc] = vb[base + i];
  }
  __syncthreads();
  if (tid < Nc) {
    float qr[DKc];
#pragma unroll
    for (int d = 0; d < DKc; d++) qr[d] = qb[base + tid * DKc + d];
    float mx = -1e30f;
    for (int mm = 0; mm < Nc; mm++) {
      float s = 0.f;
#pragma unroll
      for (int d = 0; d < DKc; d++) s += qr[d] * ksm[mm][d];
      s *= 0.17677669529663687f;  // 1/sqrt(32)
      sc[tid][mm] = s;
      mx = fmaxf(mx, s);
    }
    float ssum = 0.f;
    for (int mm = 0; mm < Nc; mm++) {
      float e = expf(sc[tid][mm] - mx);
      sc[tid][mm] = e;
      ssum += e;
    }
    float inv = 1.f / ssum;
    float acc[DKc];
#pragma unroll
    for (int d = 0; d < DKc; d++) acc[d] = 0.f;
    for (int mm = 0; mm < Nc; mm++) {
      float p = sc[tid][mm] * inv;
#pragma unroll
      for (int d = 0; d < DKc; d++) acc[d] += p * vsm[mm][d];
    }
    float* cp = ctx + ((size_t)b * Nc + tid) * Hc + hd * DKc;
#pragma unroll
    for (int d = 0; d < DKc; d++) cp[d] = acc[d];
  }
}

__global__ __launch_bounds__(128) void wo_res(
    const float* __restrict__ ctx, const float* __restrict__ Wo,
    const float* __restrict__ bo, const float* __restrict__ posi,
    float* __restrict__ mha, float* __restrict__ h1) {
  int bn = blockIdx.x;
  int h = threadIdx.x;
  __shared__ float cs[Hc];
  cs[h] = ctx[(size_t)bn * Hc + h];
  __syncthreads();
  float acc = bo[h];
  for (int k = 0; k < Hc; k++) acc += cs[k] * Wo[h * Hc + k];
  mha[(size_t)bn * Hc + h] = acc;
  h1[(size_t)bn * Hc + h] = posi[(size_t)bn * Hc + h] + acc;
}

// r7: 256 -> 512 threads (49-block launch was latency-bound on its serial
// 4096-MAC inner loop; halve per-thread work).
__global__ __launch_bounds__(512) void decov_k(
    const float* __restrict__ mha, float* __restrict__ dacc) {
  int n = blockIdx.x;
  int tid = threadIdx.x;
  __shared__ float xc[Bc][Hc];
  __shared__ float red[8];
  for (int i = tid; i < Bc * Hc; i += 512) {
    int b = i >> 7, h = i & 127;
    xc[b][h] = mha[((size_t)b * Nc + n) * Hc + h];
  }
  __syncthreads();
  if (tid < Hc) {
    float s = 0.f;
    for (int b = 0; b < Bc; b++) s += xc[b][tid];
    s *= (1.f / Bc);
    for (int b = 0; b < Bc; b++) xc[b][tid] -= s;
  }
  __syncthreads();
  float p2 = 0.f, pd = 0.f;
  for (int e = tid; e < Hc * Hc; e += 512) {
    int hh = e >> 7, gg = e & 127;
    float c = 0.f;
    for (int b = 0; b < Bc; b++) c += xc[b][hh] * xc[b][gg];
    c *= (1.f / (Bc - 1));
    float c2 = c * c;
    p2 += c2;
    if (hh == gg) pd += c2;
  }
  float s2 = bsum(p2, red, 8);
  float sdg = bsum(pd, red, 8);
  if (tid == 0) atomicAdd(dacc, 0.5f * (s2 - sdg));
}

__global__ __launch_bounds__(256) void ln2_ffn1(
    const float* __restrict__ h1, const float* __restrict__ ga, const float* __restrict__ be,
    const float* __restrict__ W1, const float* __restrict__ b1, float* __restrict__ t1) {
  int bn = blockIdx.x;
  int tid = threadIdx.x;
  __shared__ float xn[Hc];
  __shared__ float red[4];
  float xv = (tid < Hc) ? h1[(size_t)bn * Hc + tid] : 0.f;
  float m = bsum(xv, red, 4) * (1.f / Hc);
  float d = (tid < Hc) ? (xv - m) : 0.f;
  float var = bsum(d * d, red, 4) * (1.f / (Hc - 1));
  if (tid < Hc) xn[tid] = ga[tid] * d / (sqrtf(var) + 1e-7f) + be[tid];
  __syncthreads();
#pragma unroll
  for (int jj = 0; jj < 2; jj++) {
    int j = tid + jj * 256;
    float acc = b1[j];
    for (int k = 0; k < Hc; k++) acc += xn[k] * W1[j * Hc + k];
    t1[(size_t)bn * DFFc + j] = fmaxf(acc, 0.f);
  }
}

__global__ __launch_bounds__(128) void ffn2_res(
    const float* __restrict__ t1, const float* __restrict__ W2,
    const float* __restrict__ b2, const float* __restrict__ h1, float* __restrict__ h2) {
  int bn = blockIdx.x;
  int h = threadIdx.x;
  __shared__ float ts[DFFc];
  for (int i = h; i < DFFc; i += 128) ts[i] = t1[(size_t)bn * DFFc + i];
  __syncthreads();
  float acc = b2[h];
  for (int j = 0; j < DFFc; j++) acc += ts[j] * W2[h * DFFc + j];
  h2[(size_t)bn * Hc + h] = h1[(size_t)bn * Hc + h] + acc;
}

// ---------------------------------------------------------------------------
// r7 split of final_k (was 185us/dispatch at 1.5% occupancy, latency-bound:
// 64 blocks, ~12.7K serial MACs/thread, Wk rows re-read 49x uncoalesced).
// final_fkv: one block per (b,n) = 3136 blocks (same shape as ln_qkv).
// final2: per-b epilogue, wave-parallel fe dots, softmax, pooled, out.
// ---------------------------------------------------------------------------
__global__ __launch_bounds__(128) void final_fkv(
    const float* __restrict__ h2,
    const float* __restrict__ Wk, const float* __restrict__ bk,
    const float* __restrict__ Wv, const float* __restrict__ bv,
    const float* __restrict__ Wq, const float* __restrict__ bq,
    float* __restrict__ fkb, float* __restrict__ fvb, float* __restrict__ fqb) {
  int bn = blockIdx.x;
  int b = bn / Nc, n = bn - b * Nc;
  int h = threadIdx.x;
  __shared__ float xs[Hc];
  xs[h] = h2[(size_t)bn * Hc + h];
  __syncthreads();
  float k = bk[h], v = bv[h];
  const float* wkp = Wk + h * Hc;
  const float* wvp = Wv + h * Hc;
  for (int kk = 0; kk < Hc; kk++) {
    float xv = xs[kk];
    k += xv * wkp[kk];
    v += xv * wvp[kk];
  }
  fkb[(size_t)bn * Hc + h] = k;
  fvb[(size_t)bn * Hc + h] = v;
  if (n == Nc - 1) {
    float q = bq[h];
    const float* wqp = Wq + h * Hc;
    for (int kk = 0; kk < Hc; kk++) q += xs[kk] * wqp[kk];
    fqb[(size_t)b * Hc + h] = q;
  }
}

__global__ __launch_bounds__(128) void final2(
    const float* __restrict__ fkb, const float* __restrict__ fvb,
    const float* __restrict__ fqb,
    const float* __restrict__ oW, const float* __restrict__ ob,
    const float* __restrict__ dacc, float* __restrict__ out) {
  int b = blockIdx.x, h = threadIdx.x;
  int lane = h & 63, wid = h >> 6;
  __shared__ float fqs[Hc];
  __shared__ float alphas[Nc];
  __shared__ float red[2];
  __shared__ float r2[2];
  fqs[h] = fqb[(size_t)b * Hc + h];
  __syncthreads();
  // fe[n] = dot(fk[b,n,:], fq): wave-parallel, 64-lane shuffle dot (no barriers)
  for (int n = wid; n < Nc; n += 2) {
    const float* fkp = fkb + ((size_t)b * Nc + n) * Hc;
    float s = fkp[lane] * fqs[lane] + fkp[lane + 64] * fqs[lane + 64];
#pragma unroll
    for (int off = 32; off > 0; off >>= 1) s += __shfl_down(s, off);
    if (lane == 0) alphas[n] = s;
  }
  __syncthreads();
  if (h == 0) {
    float m = -1e30f;
    for (int n = 0; n < Nc; n++) m = fmaxf(m, alphas[n]);
    float ssum = 0.f;
    for (int n = 0; n < Nc; n++) {
      float e = expf(alphas[n] - m);
      alphas[n] = e;
      ssum += e;
    }
    red[0] = 1.f / ssum;
  }
  __syncthreads();
  float inv = red[0];
  // pooled[h] = sum_n alpha[n] * fv[b,n,h]   (fv reads coalesced across h)
  float pv = 0.f;
  for (int n = 0; n < Nc; n++) pv += alphas[n] * fvb[((size_t)b * Nc + n) * Hc + h];
  pv *= inv;
  float c = pv * oW[h];
#pragma unroll
  for (int off = 32; off > 0; off >>= 1) c += __shfl_down(c, off);
  if (lane == 0) r2[wid] = c;
  __syncthreads();
  if (h == 0) {
    out[b] = sigf(r2[0] + r2[1] + ob[0]);
    if (b == 0) out[Bc] = dacc[0];
  }
}

}  // namespace

extern "C" void kernel_launch(void* const* d_in, const int* in_sizes, int n_in,
                              void* d_out, int out_size, void* d_ws, size_t ws_size,
                              hipStream_t stream) {
  const float* x    = (const float*)d_in[0];
  const float* demo = (const float*)d_in[1];
  const float* gWih = (const float*)d_in[2];
  const float* gWhh = (const float*)d_in[3];
  const float* gbih = (const float*)d_in[4];
  const float* gbhh = (const float*)d_in[5];
  const float* aWt  = (const float*)d_in[6];
  const float* aWx  = (const float*)d_in[7];
  const float* aRt  = (const float*)d_in[8];
  const float* dW   = (const float*)d_in[9];
  const float* db   = (const float*)d_in[10];
  const float* mWq  = (const float*)d_in[11];
  const float* mbq  = (const float*)d_in[12];
  const float* mWk  = (const float*)d_in[13];
  const float* mbk  = (const float*)d_in[14];
  const float* mWv  = (const float*)d_in[15];
  const float* mbv  = (const float*)d_in[16];
  const float* mWo  = (const float*)d_in[17];
  const float* mbo  = (const float*)d_in[18];
  const float* l1a  = (const float*)d_in[19];
  const float* l1b  = (const float*)d_in[20];
  const float* l2a  = (const float*)d_in[21];
  const float* l2b  = (const float*)d_in[22];
  const float* fW1  = (const float*)d_in[23];
  const float* fb1  = (const float*)d_in[24];
  const float* fW2  = (const float*)d_in[25];
  const float* fb2  = (const float*)d_in[26];
  const float* fWq  = (const float*)d_in[27];
  const float* fbq  = (const float*)d_in[28];
  const float* fWk  = (const float*)d_in[29];
  const float* fbk  = (const float*)d_in[30];
  const float* fWv  = (const float*)d_in[31];
  const float* fbv  = (const float*)d_in[32];
  const float* oW   = (const float*)d_in[33];
  const float* ob   = (const float*)d_in[34];

  char* base = (char*)d_ws;
  size_t off = 0;
  auto take = [&](size_t nfloats) -> float* {
    float* r = (float*)(base + off);
    off += ((nfloats * sizeof(float)) + 255) & ~(size_t)255;
    return r;
  };
  float* dec  = take(64);
  float* hT   = take((size_t)Bc * Fc * Hc);
  float* posi = take((size_t)Bc * Nc * Hc);
  float* qb   = take((size_t)Bc * Nc * Hc);
  float* kb   = take((size_t)Bc * Nc * Hc);
  float* vb   = take((size_t)Bc * Nc * Hc);
  float* ctx  = take((size_t)Bc * Nc * Hc);
  float* mha  = take((size_t)Bc * Nc * Hc);
  float* h1   = take((size_t)Bc * Nc * Hc);
  float* t1   = take((size_t)Bc * Nc * DFFc);
  float* h2   = take((size_t)Bc * Nc * Hc);
  float* fkb  = take((size_t)Bc * Nc * Hc);
  float* fvb  = take((size_t)Bc * Nc * Hc);
  float* fqb  = take((size_t)Bc * Hc);
  size_t HsElems = (size_t)Bc * Tc * Fc * Hc;  // 37.7M
  void* HsPtr = (void*)(base + off);
  bool f32path = (ws_size >= off + HsElems * sizeof(float));

  hipMemsetAsync(dec, 0, sizeof(float), stream);

  dim3 gGru(Fc, Bc / 16);
  dim3 gAtt(Fc, Bc);
  if (f32path) {
    gru_mfma<float><<<gGru, 512, 0, stream>>>(x, gWih, gWhh, gbih, gbhh, (float*)HsPtr, hT);
    feat_attn<float><<<gAtt, 256, 0, stream>>>((const float*)HsPtr, hT, aWt, aWx, aRt, posi);
  } else {
    gru_mfma<__hip_bfloat16><<<gGru, 512, 0, stream>>>(x, gWih, gWhh, gbih, gbhh,
                                                       (__hip_bfloat16*)HsPtr, hT);
    feat_attn<__hip_bfloat16><<<gAtt, 256, 0, stream>>>((const __hip_bfloat16*)HsPtr, hT,
                                                        aWt, aWx, aRt, posi);
  }
  demo_k<<<Bc, 128, 0, stream>>>(demo, dW, db, posi);
  ln_qkv<<<Bc * Nc, 128, 0, stream>>>(posi, l1a, l1b, mWq, mbq, mWk, mbk, mWv, mbv, qb, kb, vb);
  mha_attn<<<dim3(NHc, Bc), 64, 0, stream>>>(qb, kb, vb, ctx);
  wo_res<<<Bc * Nc, 128, 0, stream>>>(ctx, mWo, mbo, posi, mha, h1);
  decov_k<<<Nc, 512, 0, stream>>>(mha, dec);
  ln2_ffn1<<<Bc * Nc, 256, 0, stream>>>(h1, l2a, l2b, fW1, fb1, t1);
  ffn2_res<<<Bc * Nc, 128, 0, stream>>>(t1, fW2, fb2, h1, h2);
  final_fkv<<<Bc * Nc, 128, 0, stream>>>(h2, fWk, fbk, fWv, fbv, fWq, fbq, fkb, fvb, fqb);
  final2<<<Bc, 128, 0, stream>>>(fkb, fvb, fqb, oW, ob, dec, (float*)d_out);
}